// Round 2
// baseline (4394.514 us; speedup 1.0000x reference)
//
#include <hip/hip_runtime.h>

// ---------------------------------------------------------------------------
// GCN 2-layer forward:  out = log_softmax( A_hat * relu(A_hat * (x W1) + b1) W2 + b2 )
// A_hat = D^-1/2 (A + I) D^-1/2 with deg computed on dst (PyG GCNConv default).
// NOTE: harness delivers integer inputs as int32 (NOT int64, despite reference).
// ---------------------------------------------------------------------------

static __device__ __forceinline__ void fma4(float4& a, float s, const float4& w) {
    a.x += s * w.x; a.y += s * w.y; a.z += s * w.z; a.w += s * w.w;
}

// --- degree histogram (int atomics) ---------------------------------------
__global__ __launch_bounds__(256) void deg_count_kernel(const int* __restrict__ dst,
                                                        int E, unsigned int* __restrict__ cnt) {
    int i = blockIdx.x * 256 + threadIdx.x;
    if (i < E) atomicAdd(&cnt[dst[i]], 1u);
}

// in-place: uint count -> float rsqrt(count+1)   (+1 = self loop)
__global__ __launch_bounds__(256) void dinv_kernel(float* buf, int N) {
    int i = blockIdx.x * 256 + threadIdx.x;
    if (i < N) {
        unsigned int c = ((const unsigned int*)buf)[i];
        buf[i] = rsqrtf((float)(c + 1u));
    }
}

// --- GEMM: Y[n,DOUT] = X[n,128] * W[128,DOUT], LDS-tiled, reg-blocked ------
template <int DOUT, int TM>
__global__ __launch_bounds__(256) void gemm_kernel(const float* __restrict__ X,
                                                   const float* __restrict__ W,
                                                   float* __restrict__ Y, int n) {
    constexpr int CG = DOUT / 4;     // float4 col groups
    constexpr int RS = 256 / CG;     // row slots
    constexpr int R  = TM / RS;      // rows per thread
    __shared__ float4 Wl[128 * CG];
    __shared__ float4 Xl[TM * 33];   // stride 33 float4s: conflict-free row reads

    int t = threadIdx.x;
    for (int i = t; i < 128 * CG; i += 256) Wl[i] = ((const float4*)W)[i];
    int row0 = blockIdx.x * TM;
    for (int i = t; i < TM * 32; i += 256) {
        int r = i >> 5, j = i & 31;
        int gr = row0 + r;
        float4 v = make_float4(0.f, 0.f, 0.f, 0.f);
        if (gr < n) v = ((const float4*)X)[(size_t)gr * 32 + j];
        Xl[r * 33 + j] = v;
    }
    __syncthreads();

    int cg = t % CG, rs = t / CG;
    float4 acc[R];
#pragma unroll
    for (int r = 0; r < R; ++r) acc[r] = make_float4(0.f, 0.f, 0.f, 0.f);

    for (int k4 = 0; k4 < 32; ++k4) {
        float4 wv[4];
#pragma unroll
        for (int kk = 0; kk < 4; ++kk) wv[kk] = Wl[(k4 * 4 + kk) * CG + cg];
#pragma unroll
        for (int r = 0; r < R; ++r) {
            int row = rs + RS * r;
            float4 xv = Xl[row * 33 + k4];
            fma4(acc[r], xv.x, wv[0]);
            fma4(acc[r], xv.y, wv[1]);
            fma4(acc[r], xv.z, wv[2]);
            fma4(acc[r], xv.w, wv[3]);
        }
    }
#pragma unroll
    for (int r = 0; r < R; ++r) {
        int gr = row0 + rs + RS * r;
        if (gr < n) ((float4*)Y)[(size_t)gr * CG + cg] = acc[r];
    }
}

// --- self-loop init: AGG[i] = dinv[i]^2 * T[i]  (fully writes AGG) ---------
template <int F>
__global__ __launch_bounds__(256) void selfloop_init_kernel(const float* __restrict__ T,
                                                            const float* __restrict__ dinv,
                                                            float* __restrict__ AGG, int N) {
    int i = blockIdx.x * 256 + threadIdx.x;   // float4 index
    int total = N * (F / 4);
    if (i >= total) return;
    int node = i / (F / 4);
    float w = dinv[node];
    w *= w;
    float4 v = ((const float4*)T)[i];
    v.x *= w; v.y *= w; v.z *= w; v.w *= w;
    ((float4*)AGG)[i] = v;
}

// --- edge scatter: AGG[dst] += dinv[src]*dinv[dst] * T[src] ----------------
template <int F>
__global__ __launch_bounds__(256) void edge_agg_kernel(const int* __restrict__ src,
                                                       const int* __restrict__ dst,
                                                       const float* __restrict__ dinv,
                                                       const float* __restrict__ T,
                                                       float* __restrict__ AGG, int E) {
    constexpr int TPE = F / 4;   // threads per edge (float4 each)
    int tid = blockIdx.x * 256 + threadIdx.x;
    int e = tid / TPE;
    if (e >= E) return;
    int c = (tid % TPE) * 4;
    int s = src[e], d = dst[e];
    float nrm = dinv[s] * dinv[d];
    float4 v = *(const float4*)(T + (size_t)s * F + c);
    float* out = AGG + (size_t)d * F + c;
    atomicAdd(out + 0, v.x * nrm);
    atomicAdd(out + 1, v.y * nrm);
    atomicAdd(out + 2, v.z * nrm);
    atomicAdd(out + 3, v.w * nrm);
}

// --- bias + relu in place (F=128) ------------------------------------------
__global__ __launch_bounds__(256) void bias_relu_kernel(float* __restrict__ H,
                                                        const float* __restrict__ b, int total4) {
    int i = blockIdx.x * 256 + threadIdx.x;
    if (i >= total4) return;
    int c4 = i & 31;   // 128/4 col groups
    float4 bv = ((const float4*)b)[c4];
    float4 v = ((float4*)H)[i];
    v.x = fmaxf(v.x + bv.x, 0.f);
    v.y = fmaxf(v.y + bv.y, 0.f);
    v.z = fmaxf(v.z + bv.z, 0.f);
    v.w = fmaxf(v.w + bv.w, 0.f);
    ((float4*)H)[i] = v;
}

// --- final: out = log_softmax(agg + b2), one wave (64 lanes) per row --------
__global__ __launch_bounds__(256) void logsoftmax_kernel(float* __restrict__ OUT,
                                                         const float* __restrict__ b, int N) {
    int row = blockIdx.x * 4 + (threadIdx.x >> 6);
    int lane = threadIdx.x & 63;
    if (row >= N) return;
    float v = OUT[(size_t)row * 64 + lane] + b[lane];
    float m = v;
#pragma unroll
    for (int off = 32; off > 0; off >>= 1) m = fmaxf(m, __shfl_xor(m, off));
    float e = __expf(v - m);
    float sum = e;
#pragma unroll
    for (int off = 32; off > 0; off >>= 1) sum += __shfl_xor(sum, off);
    OUT[(size_t)row * 64 + lane] = v - m - logf(sum);
}

extern "C" void kernel_launch(void* const* d_in, const int* in_sizes, int n_in,
                              void* d_out, int out_size, void* d_ws, size_t ws_size,
                              hipStream_t stream) {
    const float* x   = (const float*)d_in[0];
    const int*   ei  = (const int*)d_in[1];   // int32 per harness contract
    const float* W1  = (const float*)d_in[2];
    const float* b1  = (const float*)d_in[3];
    const float* W2  = (const float*)d_in[4];
    const float* b2  = (const float*)d_in[5];
    float*       out = (float*)d_out;

    const int N = in_sizes[0] / 128;      // 100000
    const int E = in_sizes[1] / 2;        // 1600000
    const int* src = ei;
    const int* dst = ei + E;

    // workspace layout: dinv [N], A [N*128], B [N*128]  (~103 MB total)
    char* ws = (char*)d_ws;
    float* dinv = (float*)ws;
    size_t offA = ((size_t)N * 4 + 255) & ~(size_t)255;
    float* A = (float*)(ws + offA);
    float* B = (float*)(ws + offA + (size_t)N * 128 * 4);

    // 1. degree -> dinv
    hipMemsetAsync(dinv, 0, (size_t)N * 4, stream);
    deg_count_kernel<<<(E + 255) / 256, 256, 0, stream>>>(dst, E, (unsigned int*)dinv);
    dinv_kernel<<<(N + 255) / 256, 256, 0, stream>>>(dinv, N);

    // 2. t1 = x @ W1
    gemm_kernel<128, 64><<<(N + 63) / 64, 256, 0, stream>>>(x, W1, A, N);

    // 3. agg1 = A_hat * t1  (self-loop init + edge scatter)
    selfloop_init_kernel<128><<<(N * 32 + 255) / 256, 256, 0, stream>>>(A, dinv, B, N);
    edge_agg_kernel<128><<<(int)(((size_t)E * 32 + 255) / 256), 256, 0, stream>>>(src, dst, dinv, A, B, E);

    // 4. h = relu(agg1 + b1)
    bias_relu_kernel<<<(N * 32 + 255) / 256, 256, 0, stream>>>(B, b1, N * 32);

    // 5. t2 = h @ W2
    gemm_kernel<64, 64><<<(N + 63) / 64, 256, 0, stream>>>(B, W2, A, N);

    // 6. agg2 = A_hat * t2 -> d_out
    selfloop_init_kernel<64><<<(N * 16 + 255) / 256, 256, 0, stream>>>(A, dinv, out, N);
    edge_agg_kernel<64><<<(int)(((size_t)E * 16 + 255) / 256), 256, 0, stream>>>(src, dst, dinv, A, out, E);

    // 7. out = log_softmax(out + b2) rowwise
    logsoftmax_kernel<<<(N + 3) / 4, 256, 0, stream>>>(out, b2, N);
}

// Round 3
// 681.452 us; speedup vs baseline: 6.4487x; 6.4487x over previous
//
#include <hip/hip_runtime.h>

// ---------------------------------------------------------------------------
// GCN 2-layer forward:  out = log_softmax( A_hat * relu(A_hat * (x W1) + b1) W2 + b2 )
// A_hat = D^-1/2 (A + I) D^-1/2, deg on dst. Edge index arrives as int32.
//
// R3: atomic scatter (76 G atomics/s wall, 4x write amplification) replaced by
// CSR pull: deg -> scan -> scatter col[], then 1 wave/node register-accumulate.
// GEMM epilogue pre-scales rows by dinv so pull needs no per-edge dinv[src];
// self-loop folds in as T'[d]. Bias+relu fused into pull1; bias+logsoftmax
// fused into pull2 (64-col row == one wave).
// ---------------------------------------------------------------------------

static __device__ __forceinline__ void fma4(float4& a, float s, const float4& w) {
    a.x += s * w.x; a.y += s * w.y; a.z += s * w.z; a.w += s * w.w;
}

// --- degree histogram (int atomics, cheap) ---------------------------------
__global__ __launch_bounds__(256) void deg_count_kernel(const int* __restrict__ dst,
                                                        int E, unsigned int* __restrict__ deg) {
    int i = blockIdx.x * 256 + threadIdx.x;
    if (i < E) atomicAdd(&deg[dst[i]], 1u);
}

__global__ __launch_bounds__(256) void dinv_kernel(const unsigned int* __restrict__ deg,
                                                   float* __restrict__ dinv, int N) {
    int i = blockIdx.x * 256 + threadIdx.x;
    if (i < N) dinv[i] = rsqrtf((float)(deg[i] + 1u));   // +1 = self loop
}

// --- hierarchical exclusive scan of deg -> cursor (=rowptr) ----------------
__global__ __launch_bounds__(256) void block_sum_kernel(const unsigned int* __restrict__ deg,
                                                        int N, unsigned int* __restrict__ bsum) {
    __shared__ unsigned int s[256];
    int t = threadIdx.x, i = blockIdx.x * 256 + t;
    s[t] = (i < N) ? deg[i] : 0u;
    __syncthreads();
    for (int off = 128; off > 0; off >>= 1) {
        if (t < off) s[t] += s[t + off];
        __syncthreads();
    }
    if (t == 0) bsum[blockIdx.x] = s[0];
}

__global__ __launch_bounds__(1024) void scan_bsum_kernel(unsigned int* bsum, int nb) {
    __shared__ unsigned int s[1024];
    int t = threadIdx.x;
    unsigned int v = (t < nb) ? bsum[t] : 0u;
    s[t] = v;
    __syncthreads();
    for (int off = 1; off < 1024; off <<= 1) {
        unsigned int u = s[t];
        if (t >= off) u += s[t - off];
        __syncthreads();
        s[t] = u;
        __syncthreads();
    }
    if (t < nb) bsum[t] = s[t] - v;   // exclusive
}

__global__ __launch_bounds__(256) void scan_final_kernel(const unsigned int* __restrict__ deg,
                                                         const unsigned int* __restrict__ bsum,
                                                         int N, unsigned int* __restrict__ cursor) {
    __shared__ unsigned int s[256];
    int t = threadIdx.x, i = blockIdx.x * 256 + t;
    unsigned int v = (i < N) ? deg[i] : 0u;
    s[t] = v;
    __syncthreads();
    for (int off = 1; off < 256; off <<= 1) {
        unsigned int u = s[t];
        if (t >= off) u += s[t - off];
        __syncthreads();
        s[t] = u;
        __syncthreads();
    }
    if (i < N) cursor[i] = bsum[blockIdx.x] + s[t] - v;   // exclusive prefix
}

// --- scatter src into CSR buckets; afterwards cursor[i] == row_end(i) ------
__global__ __launch_bounds__(256) void scatter_kernel(const int* __restrict__ src,
                                                      const int* __restrict__ dst,
                                                      unsigned int* __restrict__ cursor,
                                                      int* __restrict__ col, int E) {
    int e = blockIdx.x * 256 + threadIdx.x;
    if (e < E) {
        unsigned int pos = atomicAdd(&cursor[dst[e]], 1u);
        col[pos] = src[e];
    }
}

// --- GEMM: Y[r] = dinv[r] * (X[r,128] @ W[128,DOUT]) -----------------------
template <int DOUT, int TM>
__global__ __launch_bounds__(256) void gemm_kernel(const float* __restrict__ X,
                                                   const float* __restrict__ W,
                                                   const float* __restrict__ dinv,
                                                   float* __restrict__ Y, int n) {
    constexpr int CG = DOUT / 4;
    constexpr int RS = 256 / CG;
    constexpr int R  = TM / RS;
    __shared__ float4 Wl[128 * CG];
    __shared__ float4 Xl[TM * 33];

    int t = threadIdx.x;
    for (int i = t; i < 128 * CG; i += 256) Wl[i] = ((const float4*)W)[i];
    int row0 = blockIdx.x * TM;
    for (int i = t; i < TM * 32; i += 256) {
        int r = i >> 5, j = i & 31;
        int gr = row0 + r;
        float4 v = make_float4(0.f, 0.f, 0.f, 0.f);
        if (gr < n) v = ((const float4*)X)[(size_t)gr * 32 + j];
        Xl[r * 33 + j] = v;
    }
    __syncthreads();

    int cg = t % CG, rs = t / CG;
    float4 acc[R];
#pragma unroll
    for (int r = 0; r < R; ++r) acc[r] = make_float4(0.f, 0.f, 0.f, 0.f);

    for (int k4 = 0; k4 < 32; ++k4) {
        float4 wv[4];
#pragma unroll
        for (int kk = 0; kk < 4; ++kk) wv[kk] = Wl[(k4 * 4 + kk) * CG + cg];
#pragma unroll
        for (int r = 0; r < R; ++r) {
            float4 xv = Xl[(rs + RS * r) * 33 + k4];
            fma4(acc[r], xv.x, wv[0]);
            fma4(acc[r], xv.y, wv[1]);
            fma4(acc[r], xv.z, wv[2]);
            fma4(acc[r], xv.w, wv[3]);
        }
    }
#pragma unroll
    for (int r = 0; r < R; ++r) {
        int gr = row0 + rs + RS * r;
        if (gr < n) {
            float w = dinv[gr];
            float4 a = acc[r];
            a.x *= w; a.y *= w; a.z *= w; a.w *= w;
            ((float4*)Y)[(size_t)gr * CG + cg] = a;
        }
    }
}

// --- pull layer 1: H[d] = relu(dinv[d]*(T'[d] + sum T'[col]) + b1), F=128 --
__global__ __launch_bounds__(256) void pull_agg1_kernel(const float* __restrict__ T,
                                                        const int* __restrict__ col,
                                                        const unsigned int* __restrict__ cursor,
                                                        const unsigned int* __restrict__ deg,
                                                        const float* __restrict__ dinv,
                                                        const float* __restrict__ b1,
                                                        float* __restrict__ H, int N) {
    int node = blockIdx.x * 4 + (threadIdx.x >> 6);
    if (node >= N) return;
    int lane = threadIdx.x & 63;
    unsigned int end = cursor[node];
    unsigned int e = end - deg[node];
    const float2* Tv = (const float2*)T;
    float2 acc = Tv[(size_t)node * 64 + lane];   // self loop
    for (; e + 1 < end; e += 2) {                // 2 loads in flight
        int s0 = col[e], s1 = col[e + 1];
        float2 v0 = Tv[(size_t)s0 * 64 + lane];
        float2 v1 = Tv[(size_t)s1 * 64 + lane];
        acc.x += v0.x + v1.x;
        acc.y += v0.y + v1.y;
    }
    if (e < end) {
        float2 v0 = Tv[(size_t)col[e] * 64 + lane];
        acc.x += v0.x; acc.y += v0.y;
    }
    float w = dinv[node];
    float2 b = ((const float2*)b1)[lane];
    float2 h;
    h.x = fmaxf(fmaf(w, acc.x, b.x), 0.f);
    h.y = fmaxf(fmaf(w, acc.y, b.y), 0.f);
    ((float2*)H)[(size_t)node * 64 + lane] = h;
}

// --- pull layer 2 + logsoftmax: out[d] = lsm(dinv[d]*sum + b2), F=64 -------
__global__ __launch_bounds__(256) void pull_agg2_kernel(const float* __restrict__ T,
                                                        const int* __restrict__ col,
                                                        const unsigned int* __restrict__ cursor,
                                                        const unsigned int* __restrict__ deg,
                                                        const float* __restrict__ dinv,
                                                        const float* __restrict__ b2,
                                                        float* __restrict__ OUT, int N) {
    int node = blockIdx.x * 4 + (threadIdx.x >> 6);
    if (node >= N) return;
    int lane = threadIdx.x & 63;
    unsigned int end = cursor[node];
    unsigned int e = end - deg[node];
    float acc = T[(size_t)node * 64 + lane];     // self loop
    for (; e + 1 < end; e += 2) {
        acc += T[(size_t)col[e] * 64 + lane] + T[(size_t)col[e + 1] * 64 + lane];
    }
    if (e < end) acc += T[(size_t)col[e] * 64 + lane];

    float v = fmaf(dinv[node], acc, b2[lane]);
    float m = v;
#pragma unroll
    for (int off = 32; off > 0; off >>= 1) m = fmaxf(m, __shfl_xor(m, off));
    float ex = __expf(v - m);
    float sum = ex;
#pragma unroll
    for (int off = 32; off > 0; off >>= 1) sum += __shfl_xor(sum, off);
    OUT[(size_t)node * 64 + lane] = v - m - logf(sum);
}

extern "C" void kernel_launch(void* const* d_in, const int* in_sizes, int n_in,
                              void* d_out, int out_size, void* d_ws, size_t ws_size,
                              hipStream_t stream) {
    const float* x   = (const float*)d_in[0];
    const int*   ei  = (const int*)d_in[1];   // int32 per harness contract
    const float* W1  = (const float*)d_in[2];
    const float* b1  = (const float*)d_in[3];
    const float* W2  = (const float*)d_in[4];
    const float* b2  = (const float*)d_in[5];
    float*       out = (float*)d_out;

    const int N = in_sizes[0] / 128;      // 100000
    const int E = in_sizes[1] / 2;        // 1600000
    const int* src = ei;
    const int* dst = ei + E;
    const int nb = (N + 255) / 256;       // scan blocks (must be <= 1024)

    // workspace layout
    char* ws = (char*)d_ws;
    size_t off = 0;
    auto alloc = [&](size_t bytes) { void* p = ws + off; off = (off + bytes + 255) & ~(size_t)255; return p; };
    unsigned int* deg    = (unsigned int*)alloc((size_t)N * 4);
    float*        dinv   = (float*)alloc((size_t)N * 4);
    unsigned int* cursor = (unsigned int*)alloc((size_t)N * 4);
    unsigned int* bsum   = (unsigned int*)alloc(1024 * 4);
    int*          col    = (int*)alloc((size_t)E * 4);
    float*        A      = (float*)alloc((size_t)N * 128 * 4);  // T1', then T2' (N*64)
    float*        B      = (float*)alloc((size_t)N * 128 * 4);  // h

    // 1. degree + dinv
    hipMemsetAsync(deg, 0, (size_t)N * 4, stream);
    deg_count_kernel<<<(E + 255) / 256, 256, 0, stream>>>(dst, E, deg);
    dinv_kernel<<<nb, 256, 0, stream>>>(deg, dinv, N);

    // 2. CSR build: exclusive scan -> cursor; scatter col
    block_sum_kernel<<<nb, 256, 0, stream>>>(deg, N, bsum);
    scan_bsum_kernel<<<1, 1024, 0, stream>>>(bsum, nb);
    scan_final_kernel<<<nb, 256, 0, stream>>>(deg, bsum, N, cursor);
    scatter_kernel<<<(E + 255) / 256, 256, 0, stream>>>(src, dst, cursor, col, E);
    // now cursor[i] == row_end(i); row_start(i) = cursor[i] - deg[i]

    // 3. T1' = dinv * (x @ W1);  h = relu(dinv*(pull sum) + b1)
    gemm_kernel<128, 64><<<(N + 63) / 64, 256, 0, stream>>>(x, W1, dinv, A, N);
    pull_agg1_kernel<<<(N + 3) / 4, 256, 0, stream>>>(A, col, cursor, deg, dinv, b1, B, N);

    // 4. T2' = dinv * (h @ W2);  out = logsoftmax(dinv*(pull sum) + b2)
    gemm_kernel<64, 64><<<(N + 63) / 64, 256, 0, stream>>>(B, W2, dinv, A, N);
    pull_agg2_kernel<<<(N + 3) / 4, 256, 0, stream>>>(A, col, cursor, deg, dinv, b2, out, N);
}

// Round 4
// 541.537 us; speedup vs baseline: 8.1149x; 1.2584x over previous
//
#include <hip/hip_runtime.h>

// ---------------------------------------------------------------------------
// GCN 2-layer forward:  out = log_softmax( A_hat * relu(A_hat * (x W1) + b1) W2 + b2 )
// A_hat = D^-1/2 (A + I) D^-1/2, deg on dst. Edge index arrives as int32.
//
// R4: CSR-build scatter had 16x HBM write amplification (random 4B stores,
// cross-XCD partial lines: WRITE_SIZE 106MB for 6.4MB payload). Replaced by
// 2-pass bucket partition (dst>>9): chunked block-exclusive writes that merge
// in L2, then per-bucket LDS-cursor scatter into a 32KB window.
// ---------------------------------------------------------------------------

#define BSHIFT 9
#define BSIZE  512            // nodes per bucket; NB = ceil(N/512) = 196 < 256
#define P2_T   1024
#define P2_I   16             // edges staged per thread in partition pass

static __device__ __forceinline__ void fma4(float4& a, float s, const float4& w) {
    a.x += s * w.x; a.y += s * w.y; a.z += s * w.z; a.w += s * w.w;
}

// --- degree histogram (int atomics, cheap) ---------------------------------
__global__ __launch_bounds__(256) void deg_count_kernel(const int* __restrict__ dst,
                                                        int E, unsigned int* __restrict__ deg) {
    int i = blockIdx.x * 256 + threadIdx.x;
    if (i < E) atomicAdd(&deg[dst[i]], 1u);
}

__global__ __launch_bounds__(256) void dinv_kernel(const unsigned int* __restrict__ deg,
                                                   float* __restrict__ dinv, int N) {
    int i = blockIdx.x * 256 + threadIdx.x;
    if (i < N) dinv[i] = rsqrtf((float)(deg[i] + 1u));   // +1 = self loop
}

// --- hierarchical exclusive scan of deg -> cursor (=rowstart) --------------
__global__ __launch_bounds__(256) void block_sum_kernel(const unsigned int* __restrict__ deg,
                                                        int N, unsigned int* __restrict__ bsum) {
    __shared__ unsigned int s[256];
    int t = threadIdx.x, i = blockIdx.x * 256 + t;
    s[t] = (i < N) ? deg[i] : 0u;
    __syncthreads();
    for (int off = 128; off > 0; off >>= 1) {
        if (t < off) s[t] += s[t + off];
        __syncthreads();
    }
    if (t == 0) bsum[blockIdx.x] = s[0];
}

__global__ __launch_bounds__(1024) void scan_bsum_kernel(unsigned int* bsum, int nb) {
    __shared__ unsigned int s[1024];
    int t = threadIdx.x;
    unsigned int v = (t < nb) ? bsum[t] : 0u;
    s[t] = v;
    __syncthreads();
    for (int off = 1; off < 1024; off <<= 1) {
        unsigned int u = s[t];
        if (t >= off) u += s[t - off];
        __syncthreads();
        s[t] = u;
        __syncthreads();
    }
    if (t < nb) bsum[t] = s[t] - v;   // exclusive
}

__global__ __launch_bounds__(256) void scan_final_kernel(const unsigned int* __restrict__ deg,
                                                         const unsigned int* __restrict__ bsum,
                                                         int N, unsigned int* __restrict__ cursor) {
    __shared__ unsigned int s[256];
    int t = threadIdx.x, i = blockIdx.x * 256 + t;
    unsigned int v = (i < N) ? deg[i] : 0u;
    s[t] = v;
    __syncthreads();
    for (int off = 1; off < 256; off <<= 1) {
        unsigned int u = s[t];
        if (t >= off) u += s[t - off];
        __syncthreads();
        s[t] = u;
        __syncthreads();
    }
    if (i < N) cursor[i] = bsum[blockIdx.x] + s[t] - v;   // rowstart (exclusive prefix)
}

// --- bucket bases: bucket_base[b] = rowstart(node b*512); [NB] = E ---------
__global__ __launch_bounds__(256) void bucket_init_kernel(const unsigned int* __restrict__ cursor,
                                                          unsigned int* __restrict__ bucket_base,
                                                          unsigned int* __restrict__ bucket_fill,
                                                          int N, int NB, int E) {
    int b = blockIdx.x * 256 + threadIdx.x;
    if (b <= NB) {
        int node = b << BSHIFT;
        unsigned int v = (node < N) ? cursor[node] : (unsigned int)E;
        bucket_base[b] = v;
        if (b < NB) bucket_fill[b] = v;
    }
}

// --- pass 2: partition edges into dst-buckets, packed src|dstLocal<<17 -----
__global__ __launch_bounds__(1024) void partition_kernel(const int* __restrict__ src,
                                                         const int* __restrict__ dst,
                                                         unsigned int* __restrict__ bucket_fill,
                                                         unsigned int* __restrict__ ebuf,
                                                         int E, int NB) {
    __shared__ unsigned int hist[256];
    __shared__ unsigned int cur[256];
    int t = threadIdx.x;
    if (t < 256) hist[t] = 0u;
    __syncthreads();
    size_t base = (size_t)blockIdx.x * (P2_T * P2_I);
    int sv[P2_I], dv[P2_I];
#pragma unroll
    for (int i = 0; i < P2_I; ++i) {
        size_t idx = base + (size_t)i * P2_T + t;
        if (idx < (size_t)E) {
            sv[i] = src[idx];
            dv[i] = dst[idx];
            atomicAdd(&hist[dv[i] >> BSHIFT], 1u);
        } else dv[i] = -1;
    }
    __syncthreads();
    if (t < NB && hist[t] > 0u) cur[t] = atomicAdd(&bucket_fill[t], hist[t]);
    __syncthreads();
#pragma unroll
    for (int i = 0; i < P2_I; ++i) {
        if (dv[i] >= 0) {
            int b = dv[i] >> BSHIFT;
            unsigned int pos = atomicAdd(&cur[b], 1u);
            ebuf[pos] = (unsigned int)sv[i] | ((unsigned int)(dv[i] & (BSIZE - 1)) << 17);
        }
    }
}

// --- pass 3: per-bucket scatter with LDS cursors; cursor -> rowend ---------
__global__ __launch_bounds__(256) void bucket_scatter_kernel(const unsigned int* __restrict__ ebuf,
                                                             const unsigned int* __restrict__ bucket_base,
                                                             unsigned int* __restrict__ cursor,
                                                             int* __restrict__ col, int N) {
    __shared__ unsigned int lcur[BSIZE];
    int b = blockIdx.x, t = threadIdx.x;
    int node0 = b << BSHIFT;
    int nn = min(BSIZE, N - node0);
    for (int i = t; i < nn; i += 256) lcur[i] = cursor[node0 + i];
    __syncthreads();
    unsigned int e1 = bucket_base[b + 1];
    for (unsigned int e = bucket_base[b] + t; e < e1; e += 256) {
        unsigned int p = ebuf[e];
        unsigned int pos = atomicAdd(&lcur[p >> 17], 1u);
        col[pos] = (int)(p & 0x1FFFFu);
    }
    __syncthreads();
    for (int i = t; i < nn; i += 256) cursor[node0 + i] = lcur[i];  // = rowend
}

// --- GEMM: Y[r] = dinv[r] * (X[r,128] @ W[128,DOUT]) -----------------------
template <int DOUT, int TM>
__global__ __launch_bounds__(256) void gemm_kernel(const float* __restrict__ X,
                                                   const float* __restrict__ W,
                                                   const float* __restrict__ dinv,
                                                   float* __restrict__ Y, int n) {
    constexpr int CG = DOUT / 4;
    constexpr int RS = 256 / CG;
    constexpr int R  = TM / RS;
    __shared__ float4 Wl[128 * CG];
    __shared__ float4 Xl[TM * 33];

    int t = threadIdx.x;
    for (int i = t; i < 128 * CG; i += 256) Wl[i] = ((const float4*)W)[i];
    int row0 = blockIdx.x * TM;
    for (int i = t; i < TM * 32; i += 256) {
        int r = i >> 5, j = i & 31;
        int gr = row0 + r;
        float4 v = make_float4(0.f, 0.f, 0.f, 0.f);
        if (gr < n) v = ((const float4*)X)[(size_t)gr * 32 + j];
        Xl[r * 33 + j] = v;
    }
    __syncthreads();

    int cg = t % CG, rs = t / CG;
    float4 acc[R];
#pragma unroll
    for (int r = 0; r < R; ++r) acc[r] = make_float4(0.f, 0.f, 0.f, 0.f);

    for (int k4 = 0; k4 < 32; ++k4) {
        float4 wv[4];
#pragma unroll
        for (int kk = 0; kk < 4; ++kk) wv[kk] = Wl[(k4 * 4 + kk) * CG + cg];
#pragma unroll
        for (int r = 0; r < R; ++r) {
            float4 xv = Xl[(rs + RS * r) * 33 + k4];
            fma4(acc[r], xv.x, wv[0]);
            fma4(acc[r], xv.y, wv[1]);
            fma4(acc[r], xv.z, wv[2]);
            fma4(acc[r], xv.w, wv[3]);
        }
    }
#pragma unroll
    for (int r = 0; r < R; ++r) {
        int gr = row0 + rs + RS * r;
        if (gr < n) {
            float w = dinv[gr];
            float4 a = acc[r];
            a.x *= w; a.y *= w; a.z *= w; a.w *= w;
            ((float4*)Y)[(size_t)gr * CG + cg] = a;
        }
    }
}

// --- pull layer 1: H[d] = relu(dinv[d]*(T'[d] + sum T'[col]) + b1), F=128 --
__global__ __launch_bounds__(256) void pull_agg1_kernel(const float* __restrict__ T,
                                                        const int* __restrict__ col,
                                                        const unsigned int* __restrict__ cursor,
                                                        const unsigned int* __restrict__ deg,
                                                        const float* __restrict__ dinv,
                                                        const float* __restrict__ b1,
                                                        float* __restrict__ H, int N) {
    int node = blockIdx.x * 4 + (threadIdx.x >> 6);
    if (node >= N) return;
    int lane = threadIdx.x & 63;
    unsigned int end = cursor[node];
    unsigned int e = end - deg[node];
    const float2* Tv = (const float2*)T;
    float2 acc = Tv[(size_t)node * 64 + lane];   // self loop
    for (; e + 3 < end; e += 4) {                // 4 loads in flight
        int s0 = col[e], s1 = col[e + 1], s2 = col[e + 2], s3 = col[e + 3];
        float2 v0 = Tv[(size_t)s0 * 64 + lane];
        float2 v1 = Tv[(size_t)s1 * 64 + lane];
        float2 v2 = Tv[(size_t)s2 * 64 + lane];
        float2 v3 = Tv[(size_t)s3 * 64 + lane];
        acc.x += (v0.x + v1.x) + (v2.x + v3.x);
        acc.y += (v0.y + v1.y) + (v2.y + v3.y);
    }
    for (; e < end; ++e) {
        float2 v0 = Tv[(size_t)col[e] * 64 + lane];
        acc.x += v0.x; acc.y += v0.y;
    }
    float w = dinv[node];
    float2 b = ((const float2*)b1)[lane];
    float2 h;
    h.x = fmaxf(fmaf(w, acc.x, b.x), 0.f);
    h.y = fmaxf(fmaf(w, acc.y, b.y), 0.f);
    ((float2*)H)[(size_t)node * 64 + lane] = h;
}

// --- pull layer 2 + logsoftmax: out[d] = lsm(dinv[d]*sum + b2), F=64 -------
__global__ __launch_bounds__(256) void pull_agg2_kernel(const float* __restrict__ T,
                                                        const int* __restrict__ col,
                                                        const unsigned int* __restrict__ cursor,
                                                        const unsigned int* __restrict__ deg,
                                                        const float* __restrict__ dinv,
                                                        const float* __restrict__ b2,
                                                        float* __restrict__ OUT, int N) {
    int node = blockIdx.x * 4 + (threadIdx.x >> 6);
    if (node >= N) return;
    int lane = threadIdx.x & 63;
    unsigned int end = cursor[node];
    unsigned int e = end - deg[node];
    float acc = T[(size_t)node * 64 + lane];     // self loop
    for (; e + 3 < end; e += 4) {
        float v0 = T[(size_t)col[e] * 64 + lane];
        float v1 = T[(size_t)col[e + 1] * 64 + lane];
        float v2 = T[(size_t)col[e + 2] * 64 + lane];
        float v3 = T[(size_t)col[e + 3] * 64 + lane];
        acc += (v0 + v1) + (v2 + v3);
    }
    for (; e < end; ++e) acc += T[(size_t)col[e] * 64 + lane];

    float v = fmaf(dinv[node], acc, b2[lane]);
    float m = v;
#pragma unroll
    for (int off = 32; off > 0; off >>= 1) m = fmaxf(m, __shfl_xor(m, off));
    float ex = __expf(v - m);
    float sum = ex;
#pragma unroll
    for (int off = 32; off > 0; off >>= 1) sum += __shfl_xor(sum, off);
    OUT[(size_t)node * 64 + lane] = v - m - logf(sum);
}

extern "C" void kernel_launch(void* const* d_in, const int* in_sizes, int n_in,
                              void* d_out, int out_size, void* d_ws, size_t ws_size,
                              hipStream_t stream) {
    const float* x   = (const float*)d_in[0];
    const int*   ei  = (const int*)d_in[1];   // int32 per harness contract
    const float* W1  = (const float*)d_in[2];
    const float* b1  = (const float*)d_in[3];
    const float* W2  = (const float*)d_in[4];
    const float* b2  = (const float*)d_in[5];
    float*       out = (float*)d_out;

    const int N = in_sizes[0] / 128;      // 100000
    const int E = in_sizes[1] / 2;        // 1600000
    const int* src = ei;
    const int* dst = ei + E;
    const int nb = (N + 255) / 256;       // scan blocks (<= 1024)
    const int NB = (N + BSIZE - 1) >> BSHIFT;   // dst buckets (196 <= 256)

    // workspace layout
    char* ws = (char*)d_ws;
    size_t off = 0;
    auto alloc = [&](size_t bytes) { void* p = ws + off; off = (off + bytes + 255) & ~(size_t)255; return p; };
    unsigned int* deg    = (unsigned int*)alloc((size_t)N * 4);
    float*        dinv   = (float*)alloc((size_t)N * 4);
    unsigned int* cursor = (unsigned int*)alloc((size_t)N * 4);
    unsigned int* bsum   = (unsigned int*)alloc(1024 * 4);
    unsigned int* bb     = (unsigned int*)alloc(257 * 4);      // bucket_base
    unsigned int* bf     = (unsigned int*)alloc(256 * 4);      // bucket_fill
    int*          col    = (int*)alloc((size_t)E * 4);
    float*        A      = (float*)alloc((size_t)N * 128 * 4); // T1'/T2'; ebuf aliases (dead before gemm1)
    float*        B      = (float*)alloc((size_t)N * 128 * 4); // h
    unsigned int* ebuf   = (unsigned int*)A;

    // 1. degree + dinv
    hipMemsetAsync(deg, 0, (size_t)N * 4, stream);
    deg_count_kernel<<<(E + 255) / 256, 256, 0, stream>>>(dst, E, deg);
    dinv_kernel<<<nb, 256, 0, stream>>>(deg, dinv, N);

    // 2. CSR build: scan -> rowstart; bucket partition; per-bucket scatter
    block_sum_kernel<<<nb, 256, 0, stream>>>(deg, N, bsum);
    scan_bsum_kernel<<<1, 1024, 0, stream>>>(bsum, nb);
    scan_final_kernel<<<nb, 256, 0, stream>>>(deg, bsum, N, cursor);
    bucket_init_kernel<<<2, 256, 0, stream>>>(cursor, bb, bf, N, NB, E);
    partition_kernel<<<(E + P2_T * P2_I - 1) / (P2_T * P2_I), P2_T, 0, stream>>>(src, dst, bf, ebuf, E, NB);
    bucket_scatter_kernel<<<NB, 256, 0, stream>>>(ebuf, bb, cursor, col, N);
    // now cursor[i] == rowend(i); rowstart(i) = cursor[i] - deg[i]

    // 3. T1' = dinv * (x @ W1);  h = relu(dinv*(pull sum) + b1)
    gemm_kernel<128, 64><<<(N + 63) / 64, 256, 0, stream>>>(x, W1, dinv, A, N);
    pull_agg1_kernel<<<(N + 3) / 4, 256, 0, stream>>>(A, col, cursor, deg, dinv, b1, B, N);

    // 4. T2' = dinv * (h @ W2);  out = logsoftmax(dinv*(pull sum) + b2)
    gemm_kernel<64, 64><<<(N + 63) / 64, 256, 0, stream>>>(B, W2, dinv, A, N);
    pull_agg2_kernel<<<(N + 3) / 4, 256, 0, stream>>>(A, col, cursor, deg, dinv, b2, out, N);
}

// Round 5
// 481.234 us; speedup vs baseline: 9.1318x; 1.1253x over previous
//
#include <hip/hip_runtime.h>

// ---------------------------------------------------------------------------
// GCN 2-layer forward:  out = log_softmax( A_hat * relu(A_hat * (x W1) + b1) W2 + b2 )
// A_hat = D^-1/2 (A + I) D^-1/2, deg on dst. Edge index arrives as int32.
//
// R5: old GEMM staged all of W (64KB) + X tile (33KB) in LDS -> 99KB -> 1
// block/CU, 9.9% occupancy, 126us (roofline ~25us). Now K-chunked (KC=32):
// LDS <= 26KB, 4 blocks/CU. Xl stride 9 float4/row -> banks 4r%32, no
// conflicts. W chunk re-reads hit L2 (W is 64KB, resident).
// ---------------------------------------------------------------------------

#define BSHIFT 9
#define BSIZE  512            // nodes per bucket; NB = ceil(N/512) = 196 < 256
#define P2_T   1024
#define P2_I   16             // edges staged per thread in partition pass

static __device__ __forceinline__ void fma4(float4& a, float s, const float4& w) {
    a.x += s * w.x; a.y += s * w.y; a.z += s * w.z; a.w += s * w.w;
}

// --- degree histogram (int atomics, cheap) ---------------------------------
__global__ __launch_bounds__(256) void deg_count_kernel(const int* __restrict__ dst,
                                                        int E, unsigned int* __restrict__ deg) {
    int i = blockIdx.x * 256 + threadIdx.x;
    if (i < E) atomicAdd(&deg[dst[i]], 1u);
}

__global__ __launch_bounds__(256) void dinv_kernel(const unsigned int* __restrict__ deg,
                                                   float* __restrict__ dinv, int N) {
    int i = blockIdx.x * 256 + threadIdx.x;
    if (i < N) dinv[i] = rsqrtf((float)(deg[i] + 1u));   // +1 = self loop
}

// --- hierarchical exclusive scan of deg -> cursor (=rowstart) --------------
__global__ __launch_bounds__(256) void block_sum_kernel(const unsigned int* __restrict__ deg,
                                                        int N, unsigned int* __restrict__ bsum) {
    __shared__ unsigned int s[256];
    int t = threadIdx.x, i = blockIdx.x * 256 + t;
    s[t] = (i < N) ? deg[i] : 0u;
    __syncthreads();
    for (int off = 128; off > 0; off >>= 1) {
        if (t < off) s[t] += s[t + off];
        __syncthreads();
    }
    if (t == 0) bsum[blockIdx.x] = s[0];
}

__global__ __launch_bounds__(1024) void scan_bsum_kernel(unsigned int* bsum, int nb) {
    __shared__ unsigned int s[1024];
    int t = threadIdx.x;
    unsigned int v = (t < nb) ? bsum[t] : 0u;
    s[t] = v;
    __syncthreads();
    for (int off = 1; off < 1024; off <<= 1) {
        unsigned int u = s[t];
        if (t >= off) u += s[t - off];
        __syncthreads();
        s[t] = u;
        __syncthreads();
    }
    if (t < nb) bsum[t] = s[t] - v;   // exclusive
}

__global__ __launch_bounds__(256) void scan_final_kernel(const unsigned int* __restrict__ deg,
                                                         const unsigned int* __restrict__ bsum,
                                                         int N, unsigned int* __restrict__ cursor) {
    __shared__ unsigned int s[256];
    int t = threadIdx.x, i = blockIdx.x * 256 + t;
    unsigned int v = (i < N) ? deg[i] : 0u;
    s[t] = v;
    __syncthreads();
    for (int off = 1; off < 256; off <<= 1) {
        unsigned int u = s[t];
        if (t >= off) u += s[t - off];
        __syncthreads();
        s[t] = u;
        __syncthreads();
    }
    if (i < N) cursor[i] = bsum[blockIdx.x] + s[t] - v;   // rowstart (exclusive prefix)
}

// --- bucket bases: bucket_base[b] = rowstart(node b*512); [NB] = E ---------
__global__ __launch_bounds__(256) void bucket_init_kernel(const unsigned int* __restrict__ cursor,
                                                          unsigned int* __restrict__ bucket_base,
                                                          unsigned int* __restrict__ bucket_fill,
                                                          int N, int NB, int E) {
    int b = blockIdx.x * 256 + threadIdx.x;
    if (b <= NB) {
        int node = b << BSHIFT;
        unsigned int v = (node < N) ? cursor[node] : (unsigned int)E;
        bucket_base[b] = v;
        if (b < NB) bucket_fill[b] = v;
    }
}

// --- pass 2: partition edges into dst-buckets, packed src|dstLocal<<17 -----
__global__ __launch_bounds__(1024) void partition_kernel(const int* __restrict__ src,
                                                         const int* __restrict__ dst,
                                                         unsigned int* __restrict__ bucket_fill,
                                                         unsigned int* __restrict__ ebuf,
                                                         int E, int NB) {
    __shared__ unsigned int hist[256];
    __shared__ unsigned int cur[256];
    int t = threadIdx.x;
    if (t < 256) hist[t] = 0u;
    __syncthreads();
    size_t base = (size_t)blockIdx.x * (P2_T * P2_I);
    int sv[P2_I], dv[P2_I];
#pragma unroll
    for (int i = 0; i < P2_I; ++i) {
        size_t idx = base + (size_t)i * P2_T + t;
        if (idx < (size_t)E) {
            sv[i] = src[idx];
            dv[i] = dst[idx];
            atomicAdd(&hist[dv[i] >> BSHIFT], 1u);
        } else dv[i] = -1;
    }
    __syncthreads();
    if (t < NB && hist[t] > 0u) cur[t] = atomicAdd(&bucket_fill[t], hist[t]);
    __syncthreads();
#pragma unroll
    for (int i = 0; i < P2_I; ++i) {
        if (dv[i] >= 0) {
            int b = dv[i] >> BSHIFT;
            unsigned int pos = atomicAdd(&cur[b], 1u);
            ebuf[pos] = (unsigned int)sv[i] | ((unsigned int)(dv[i] & (BSIZE - 1)) << 17);
        }
    }
}

// --- pass 3: per-bucket scatter with LDS cursors; cursor -> rowend ---------
__global__ __launch_bounds__(256) void bucket_scatter_kernel(const unsigned int* __restrict__ ebuf,
                                                             const unsigned int* __restrict__ bucket_base,
                                                             unsigned int* __restrict__ cursor,
                                                             int* __restrict__ col, int N) {
    __shared__ unsigned int lcur[BSIZE];
    int b = blockIdx.x, t = threadIdx.x;
    int node0 = b << BSHIFT;
    int nn = min(BSIZE, N - node0);
    for (int i = t; i < nn; i += 256) lcur[i] = cursor[node0 + i];
    __syncthreads();
    unsigned int e1 = bucket_base[b + 1];
    for (unsigned int e = bucket_base[b] + t; e < e1; e += 256) {
        unsigned int p = ebuf[e];
        unsigned int pos = atomicAdd(&lcur[p >> 17], 1u);
        col[pos] = (int)(p & 0x1FFFFu);
    }
    __syncthreads();
    for (int i = t; i < nn; i += 256) cursor[node0 + i] = lcur[i];  // = rowend
}

// --- GEMM: Y[r] = dinv[r] * (X[r,128] @ W[128,DOUT]), K-chunked ------------
template <int DOUT, int TM>
__global__ __launch_bounds__(256, 4) void gemm_kernel(const float* __restrict__ X,
                                                      const float* __restrict__ W,
                                                      const float* __restrict__ dinv,
                                                      float* __restrict__ Y, int n) {
    constexpr int CG = DOUT / 4;     // float4 col groups (32 / 16)
    constexpr int RS = 256 / CG;     // row slots (8 / 16)
    constexpr int R  = TM / RS;      // rows per thread (8 / 4 at TM=64)
    constexpr int KC = 32;           // K-chunk (floats)
    __shared__ float4 Wl[KC * CG];   // 16 KB / 8 KB
    __shared__ float4 Xl[TM * 9];    // 8 used + 1 pad per row -> banks 4r%32

    int t = threadIdx.x;
    int row0 = blockIdx.x * TM;
    int cg = t % CG, rs = t / CG;
    float4 acc[R];
#pragma unroll
    for (int r = 0; r < R; ++r) acc[r] = make_float4(0.f, 0.f, 0.f, 0.f);

    for (int kc = 0; kc < 128 / KC; ++kc) {
        // stage W chunk [KC x DOUT] and X chunk [TM x KC]
        for (int i = t; i < KC * CG; i += 256) {
            int k = i / CG, c = i % CG;
            Wl[i] = ((const float4*)W)[(size_t)(kc * KC + k) * CG + c];
        }
        for (int i = t; i < TM * 8; i += 256) {
            int r = i >> 3, j = i & 7;
            int gr = row0 + r;
            float4 v = make_float4(0.f, 0.f, 0.f, 0.f);
            if (gr < n) v = ((const float4*)X)[(size_t)gr * 32 + kc * 8 + j];
            Xl[r * 9 + j] = v;
        }
        __syncthreads();

#pragma unroll
        for (int k4 = 0; k4 < 8; ++k4) {
            float4 wv[4];
#pragma unroll
            for (int kk = 0; kk < 4; ++kk) wv[kk] = Wl[(k4 * 4 + kk) * CG + cg];
#pragma unroll
            for (int r = 0; r < R; ++r) {
                float4 xv = Xl[(rs + RS * r) * 9 + k4];
                fma4(acc[r], xv.x, wv[0]);
                fma4(acc[r], xv.y, wv[1]);
                fma4(acc[r], xv.z, wv[2]);
                fma4(acc[r], xv.w, wv[3]);
            }
        }
        __syncthreads();
    }
#pragma unroll
    for (int r = 0; r < R; ++r) {
        int gr = row0 + rs + RS * r;
        if (gr < n) {
            float w = dinv[gr];
            float4 a = acc[r];
            a.x *= w; a.y *= w; a.z *= w; a.w *= w;
            ((float4*)Y)[(size_t)gr * CG + cg] = a;
        }
    }
}

// --- pull layer 1: H[d] = relu(dinv[d]*(T'[d] + sum T'[col]) + b1), F=128 --
__global__ __launch_bounds__(256) void pull_agg1_kernel(const float* __restrict__ T,
                                                        const int* __restrict__ col,
                                                        const unsigned int* __restrict__ cursor,
                                                        const unsigned int* __restrict__ deg,
                                                        const float* __restrict__ dinv,
                                                        const float* __restrict__ b1,
                                                        float* __restrict__ H, int N) {
    int node = blockIdx.x * 4 + (threadIdx.x >> 6);
    if (node >= N) return;
    int lane = threadIdx.x & 63;
    unsigned int end = cursor[node];
    unsigned int e = end - deg[node];
    const float2* Tv = (const float2*)T;
    float2 acc = Tv[(size_t)node * 64 + lane];   // self loop
    for (; e + 3 < end; e += 4) {                // 4 loads in flight
        int s0 = col[e], s1 = col[e + 1], s2 = col[e + 2], s3 = col[e + 3];
        float2 v0 = Tv[(size_t)s0 * 64 + lane];
        float2 v1 = Tv[(size_t)s1 * 64 + lane];
        float2 v2 = Tv[(size_t)s2 * 64 + lane];
        float2 v3 = Tv[(size_t)s3 * 64 + lane];
        acc.x += (v0.x + v1.x) + (v2.x + v3.x);
        acc.y += (v0.y + v1.y) + (v2.y + v3.y);
    }
    for (; e < end; ++e) {
        float2 v0 = Tv[(size_t)col[e] * 64 + lane];
        acc.x += v0.x; acc.y += v0.y;
    }
    float w = dinv[node];
    float2 b = ((const float2*)b1)[lane];
    float2 h;
    h.x = fmaxf(fmaf(w, acc.x, b.x), 0.f);
    h.y = fmaxf(fmaf(w, acc.y, b.y), 0.f);
    ((float2*)H)[(size_t)node * 64 + lane] = h;
}

// --- pull layer 2 + logsoftmax: out[d] = lsm(dinv[d]*sum + b2), F=64 -------
__global__ __launch_bounds__(256) void pull_agg2_kernel(const float* __restrict__ T,
                                                        const int* __restrict__ col,
                                                        const unsigned int* __restrict__ cursor,
                                                        const unsigned int* __restrict__ deg,
                                                        const float* __restrict__ dinv,
                                                        const float* __restrict__ b2,
                                                        float* __restrict__ OUT, int N) {
    int node = blockIdx.x * 4 + (threadIdx.x >> 6);
    if (node >= N) return;
    int lane = threadIdx.x & 63;
    unsigned int end = cursor[node];
    unsigned int e = end - deg[node];
    float acc = T[(size_t)node * 64 + lane];     // self loop
    for (; e + 3 < end; e += 4) {
        float v0 = T[(size_t)col[e] * 64 + lane];
        float v1 = T[(size_t)col[e + 1] * 64 + lane];
        float v2 = T[(size_t)col[e + 2] * 64 + lane];
        float v3 = T[(size_t)col[e + 3] * 64 + lane];
        acc += (v0 + v1) + (v2 + v3);
    }
    for (; e < end; ++e) acc += T[(size_t)col[e] * 64 + lane];

    float v = fmaf(dinv[node], acc, b2[lane]);
    float m = v;
#pragma unroll
    for (int off = 32; off > 0; off >>= 1) m = fmaxf(m, __shfl_xor(m, off));
    float ex = __expf(v - m);
    float sum = ex;
#pragma unroll
    for (int off = 32; off > 0; off >>= 1) sum += __shfl_xor(sum, off);
    OUT[(size_t)node * 64 + lane] = v - m - logf(sum);
}

extern "C" void kernel_launch(void* const* d_in, const int* in_sizes, int n_in,
                              void* d_out, int out_size, void* d_ws, size_t ws_size,
                              hipStream_t stream) {
    const float* x   = (const float*)d_in[0];
    const int*   ei  = (const int*)d_in[1];   // int32 per harness contract
    const float* W1  = (const float*)d_in[2];
    const float* b1  = (const float*)d_in[3];
    const float* W2  = (const float*)d_in[4];
    const float* b2  = (const float*)d_in[5];
    float*       out = (float*)d_out;

    const int N = in_sizes[0] / 128;      // 100000
    const int E = in_sizes[1] / 2;        // 1600000
    const int* src = ei;
    const int* dst = ei + E;
    const int nb = (N + 255) / 256;       // scan blocks (<= 1024)
    const int NB = (N + BSIZE - 1) >> BSHIFT;   // dst buckets (196 <= 256)

    // workspace layout
    char* ws = (char*)d_ws;
    size_t off = 0;
    auto alloc = [&](size_t bytes) { void* p = ws + off; off = (off + bytes + 255) & ~(size_t)255; return p; };
    unsigned int* deg    = (unsigned int*)alloc((size_t)N * 4);
    float*        dinv   = (float*)alloc((size_t)N * 4);
    unsigned int* cursor = (unsigned int*)alloc((size_t)N * 4);
    unsigned int* bsum   = (unsigned int*)alloc(1024 * 4);
    unsigned int* bb     = (unsigned int*)alloc(257 * 4);      // bucket_base
    unsigned int* bf     = (unsigned int*)alloc(256 * 4);      // bucket_fill
    int*          col    = (int*)alloc((size_t)E * 4);
    float*        A      = (float*)alloc((size_t)N * 128 * 4); // T1'/T2'; ebuf aliases (dead before gemm1)
    float*        B      = (float*)alloc((size_t)N * 128 * 4); // h
    unsigned int* ebuf   = (unsigned int*)A;

    // 1. degree + dinv
    hipMemsetAsync(deg, 0, (size_t)N * 4, stream);
    deg_count_kernel<<<(E + 255) / 256, 256, 0, stream>>>(dst, E, deg);
    dinv_kernel<<<nb, 256, 0, stream>>>(deg, dinv, N);

    // 2. CSR build: scan -> rowstart; bucket partition; per-bucket scatter
    block_sum_kernel<<<nb, 256, 0, stream>>>(deg, N, bsum);
    scan_bsum_kernel<<<1, 1024, 0, stream>>>(bsum, nb);
    scan_final_kernel<<<nb, 256, 0, stream>>>(deg, bsum, N, cursor);
    bucket_init_kernel<<<2, 256, 0, stream>>>(cursor, bb, bf, N, NB, E);
    partition_kernel<<<(E + P2_T * P2_I - 1) / (P2_T * P2_I), P2_T, 0, stream>>>(src, dst, bf, ebuf, E, NB);
    bucket_scatter_kernel<<<NB, 256, 0, stream>>>(ebuf, bb, cursor, col, N);
    // now cursor[i] == rowend(i); rowstart(i) = cursor[i] - deg[i]

    // 3. T1' = dinv * (x @ W1);  h = relu(dinv*(pull sum) + b1)
    gemm_kernel<128, 64><<<(N + 63) / 64, 256, 0, stream>>>(x, W1, dinv, A, N);
    pull_agg1_kernel<<<(N + 3) / 4, 256, 0, stream>>>(A, col, cursor, deg, dinv, b1, B, N);

    // 4. T2' = dinv * (h @ W2);  out = logsoftmax(dinv*(pull sum) + b2)
    gemm_kernel<64, 64><<<(N + 63) / 64, 256, 0, stream>>>(B, W2, dinv, A, N);
    pull_agg2_kernel<<<(N + 3) / 4, 256, 0, stream>>>(A, col, cursor, deg, dinv, b2, out, N);
}

// Round 7
// 400.796 us; speedup vs baseline: 10.9645x; 1.2007x over previous
//
#include <hip/hip_runtime.h>
#include <hip/hip_fp16.h>

// ---------------------------------------------------------------------------
// GCN 2-layer forward:  out = log_softmax( A_hat * relu(A_hat * (x W1) + b1) W2 + b2 )
// A_hat = D^-1/2 (A + I) D^-1/2, deg on dst. Edge index arrives as int32.
//
// R7: r6 (fp16 intermediates) crashed; static bounds audit found nothing, so
// suspect codegen on uint2 type-punning / if-constexpr templated GEMM.
// Same fp16 plan, de-exotified: concrete gemm1 (f32->f16) + gemm2 (f16->f16),
// all fp16 IO via plain __half2. fp32 accumulate everywhere.
// ---------------------------------------------------------------------------

#define BSHIFT 9
#define BSIZE  512            // nodes per bucket; NB = ceil(N/512) = 196 < 256
#define P2_T   1024
#define P2_I   16             // edges staged per thread in partition pass

static __device__ __forceinline__ void fma4(float4& a, float s, const float4& w) {
    a.x += s * w.x; a.y += s * w.y; a.z += s * w.z; a.w += s * w.w;
}

// --- degree histogram (int atomics, cheap) ---------------------------------
__global__ __launch_bounds__(256) void deg_count_kernel(const int* __restrict__ dst,
                                                        int E, unsigned int* __restrict__ deg) {
    int i = blockIdx.x * 256 + threadIdx.x;
    if (i < E) atomicAdd(&deg[dst[i]], 1u);
}

__global__ __launch_bounds__(256) void dinv_kernel(const unsigned int* __restrict__ deg,
                                                   float* __restrict__ dinv, int N) {
    int i = blockIdx.x * 256 + threadIdx.x;
    if (i < N) dinv[i] = rsqrtf((float)(deg[i] + 1u));   // +1 = self loop
}

// --- hierarchical exclusive scan of deg -> cursor (=rowstart) --------------
__global__ __launch_bounds__(256) void block_sum_kernel(const unsigned int* __restrict__ deg,
                                                        int N, unsigned int* __restrict__ bsum) {
    __shared__ unsigned int s[256];
    int t = threadIdx.x, i = blockIdx.x * 256 + t;
    s[t] = (i < N) ? deg[i] : 0u;
    __syncthreads();
    for (int off = 128; off > 0; off >>= 1) {
        if (t < off) s[t] += s[t + off];
        __syncthreads();
    }
    if (t == 0) bsum[blockIdx.x] = s[0];
}

__global__ __launch_bounds__(1024) void scan_bsum_kernel(unsigned int* bsum, int nb) {
    __shared__ unsigned int s[1024];
    int t = threadIdx.x;
    unsigned int v = (t < nb) ? bsum[t] : 0u;
    s[t] = v;
    __syncthreads();
    for (int off = 1; off < 1024; off <<= 1) {
        unsigned int u = s[t];
        if (t >= off) u += s[t - off];
        __syncthreads();
        s[t] = u;
        __syncthreads();
    }
    if (t < nb) bsum[t] = s[t] - v;   // exclusive
}

__global__ __launch_bounds__(256) void scan_final_kernel(const unsigned int* __restrict__ deg,
                                                         const unsigned int* __restrict__ bsum,
                                                         int N, unsigned int* __restrict__ cursor) {
    __shared__ unsigned int s[256];
    int t = threadIdx.x, i = blockIdx.x * 256 + t;
    unsigned int v = (i < N) ? deg[i] : 0u;
    s[t] = v;
    __syncthreads();
    for (int off = 1; off < 256; off <<= 1) {
        unsigned int u = s[t];
        if (t >= off) u += s[t - off];
        __syncthreads();
        s[t] = u;
        __syncthreads();
    }
    if (i < N) cursor[i] = bsum[blockIdx.x] + s[t] - v;   // rowstart (exclusive prefix)
}

// --- bucket bases: bucket_base[b] = rowstart(node b*512); [NB] = E ---------
__global__ __launch_bounds__(256) void bucket_init_kernel(const unsigned int* __restrict__ cursor,
                                                          unsigned int* __restrict__ bucket_base,
                                                          unsigned int* __restrict__ bucket_fill,
                                                          int N, int NB, int E) {
    int b = blockIdx.x * 256 + threadIdx.x;
    if (b <= NB) {
        int node = b << BSHIFT;
        unsigned int v = (node < N) ? cursor[node] : (unsigned int)E;
        bucket_base[b] = v;
        if (b < NB) bucket_fill[b] = v;
    }
}

// --- pass 2: partition edges into dst-buckets, packed src|dstLocal<<17 -----
__global__ __launch_bounds__(1024) void partition_kernel(const int* __restrict__ src,
                                                         const int* __restrict__ dst,
                                                         unsigned int* __restrict__ bucket_fill,
                                                         unsigned int* __restrict__ ebuf,
                                                         int E, int NB) {
    __shared__ unsigned int hist[256];
    __shared__ unsigned int cur[256];
    int t = threadIdx.x;
    if (t < 256) hist[t] = 0u;
    __syncthreads();
    size_t base = (size_t)blockIdx.x * (P2_T * P2_I);
    int sv[P2_I], dv[P2_I];
#pragma unroll
    for (int i = 0; i < P2_I; ++i) {
        size_t idx = base + (size_t)i * P2_T + t;
        if (idx < (size_t)E) {
            sv[i] = src[idx];
            dv[i] = dst[idx];
            atomicAdd(&hist[dv[i] >> BSHIFT], 1u);
        } else dv[i] = -1;
    }
    __syncthreads();
    if (t < NB && hist[t] > 0u) cur[t] = atomicAdd(&bucket_fill[t], hist[t]);
    __syncthreads();
#pragma unroll
    for (int i = 0; i < P2_I; ++i) {
        if (dv[i] >= 0) {
            int b = dv[i] >> BSHIFT;
            unsigned int pos = atomicAdd(&cur[b], 1u);
            ebuf[pos] = (unsigned int)sv[i] | ((unsigned int)(dv[i] & (BSIZE - 1)) << 17);
        }
    }
}

// --- pass 3: per-bucket scatter with LDS cursors; cursor -> rowend ---------
__global__ __launch_bounds__(256) void bucket_scatter_kernel(const unsigned int* __restrict__ ebuf,
                                                             const unsigned int* __restrict__ bucket_base,
                                                             unsigned int* __restrict__ cursor,
                                                             int* __restrict__ col, int N) {
    __shared__ unsigned int lcur[BSIZE];
    int b = blockIdx.x, t = threadIdx.x;
    int node0 = b << BSHIFT;
    int nn = min(BSIZE, N - node0);
    for (int i = t; i < nn; i += 256) lcur[i] = cursor[node0 + i];
    __syncthreads();
    unsigned int e1 = bucket_base[b + 1];
    for (unsigned int e = bucket_base[b] + t; e < e1; e += 256) {
        unsigned int p = ebuf[e];
        unsigned int pos = atomicAdd(&lcur[p >> 17], 1u);
        col[pos] = (int)(p & 0x1FFFFu);
    }
    __syncthreads();
    for (int i = t; i < nn; i += 256) cursor[node0 + i] = lcur[i];  // = rowend
}

// --- GEMM1: Y[r,128] = f16( dinv[r] * (X[r,128] @ W[128,128]) ) ------------
__global__ __launch_bounds__(256, 4) void gemm1_kernel(const float* __restrict__ X,
                                                       const float* __restrict__ W,
                                                       const float* __restrict__ dinv,
                                                       __half* __restrict__ Y, int n) {
    constexpr int CG = 32, RS = 8, R = 8, KC = 32;
    __shared__ float4 Wl[KC * CG];   // 16 KB
    __shared__ float4 Xl[64 * 9];    // 9 KB, stride 9 -> banks 4r%32

    int t = threadIdx.x;
    int row0 = blockIdx.x * 64;
    int cg = t % CG, rs = t / CG;
    float4 acc[R];
#pragma unroll
    for (int r = 0; r < R; ++r) acc[r] = make_float4(0.f, 0.f, 0.f, 0.f);

    for (int kc = 0; kc < 4; ++kc) {
        for (int i = t; i < KC * CG; i += 256) {
            int k = i / CG, c = i % CG;
            Wl[i] = ((const float4*)W)[(size_t)(kc * KC + k) * CG + c];
        }
        for (int i = t; i < 64 * 8; i += 256) {
            int r = i >> 3, j = i & 7;
            int gr = row0 + r;
            float4 v = make_float4(0.f, 0.f, 0.f, 0.f);
            if (gr < n) v = ((const float4*)X)[(size_t)gr * 32 + kc * 8 + j];
            Xl[r * 9 + j] = v;
        }
        __syncthreads();
#pragma unroll
        for (int k4 = 0; k4 < 8; ++k4) {
            float4 wv[4];
#pragma unroll
            for (int kk = 0; kk < 4; ++kk) wv[kk] = Wl[(k4 * 4 + kk) * CG + cg];
#pragma unroll
            for (int r = 0; r < R; ++r) {
                float4 xv = Xl[(rs + RS * r) * 9 + k4];
                fma4(acc[r], xv.x, wv[0]);
                fma4(acc[r], xv.y, wv[1]);
                fma4(acc[r], xv.z, wv[2]);
                fma4(acc[r], xv.w, wv[3]);
            }
        }
        __syncthreads();
    }
#pragma unroll
    for (int r = 0; r < R; ++r) {
        int gr = row0 + rs + RS * r;
        if (gr < n) {
            float w = dinv[gr];
            float4 a = acc[r];
            __half2* Yv = (__half2*)(Y + (size_t)gr * 128 + cg * 4);
            Yv[0] = __floats2half2_rn(a.x * w, a.y * w);
            Yv[1] = __floats2half2_rn(a.z * w, a.w * w);
        }
    }
}

// --- GEMM2: Y[r,64] = f16( dinv[r] * (Xh[r,128] @ W[128,64]) ) -------------
__global__ __launch_bounds__(256, 4) void gemm2_kernel(const __half* __restrict__ X,
                                                       const float* __restrict__ W,
                                                       const float* __restrict__ dinv,
                                                       __half* __restrict__ Y, int n) {
    constexpr int CG = 16, RS = 16, R = 4, KC = 32;
    __shared__ float4 Wl[KC * CG];   // 8 KB
    __shared__ float4 Xl[64 * 9];    // 9 KB

    int t = threadIdx.x;
    int row0 = blockIdx.x * 64;
    int cg = t % CG, rs = t / CG;
    float4 acc[R];
#pragma unroll
    for (int r = 0; r < R; ++r) acc[r] = make_float4(0.f, 0.f, 0.f, 0.f);

    for (int kc = 0; kc < 4; ++kc) {
        for (int i = t; i < KC * CG; i += 256) {
            int k = i / CG, c = i % CG;
            Wl[i] = ((const float4*)W)[(size_t)(kc * KC + k) * CG + c];
        }
        for (int i = t; i < 64 * 8; i += 256) {
            int r = i >> 3, j = i & 7;
            int gr = row0 + r;
            float4 v = make_float4(0.f, 0.f, 0.f, 0.f);
            if (gr < n) {
                const __half2* xp = (const __half2*)(X + (size_t)gr * 128 + (kc * 8 + j) * 4);
                float2 lo = __half22float2(xp[0]);
                float2 hi = __half22float2(xp[1]);
                v = make_float4(lo.x, lo.y, hi.x, hi.y);
            }
            Xl[r * 9 + j] = v;
        }
        __syncthreads();
#pragma unroll
        for (int k4 = 0; k4 < 8; ++k4) {
            float4 wv[4];
#pragma unroll
            for (int kk = 0; kk < 4; ++kk) wv[kk] = Wl[(k4 * 4 + kk) * CG + cg];
#pragma unroll
            for (int r = 0; r < R; ++r) {
                float4 xv = Xl[(rs + RS * r) * 9 + k4];
                fma4(acc[r], xv.x, wv[0]);
                fma4(acc[r], xv.y, wv[1]);
                fma4(acc[r], xv.z, wv[2]);
                fma4(acc[r], xv.w, wv[3]);
            }
        }
        __syncthreads();
    }
#pragma unroll
    for (int r = 0; r < R; ++r) {
        int gr = row0 + rs + RS * r;
        if (gr < n) {
            float w = dinv[gr];
            float4 a = acc[r];
            __half2* Yv = (__half2*)(Y + (size_t)gr * 64 + cg * 4);
            Yv[0] = __floats2half2_rn(a.x * w, a.y * w);
            Yv[1] = __floats2half2_rn(a.z * w, a.w * w);
        }
    }
}

// --- pull layer 1: H[d] = relu(dinv[d]*(T'[d] + sum T'[col]) + b1), F=128 --
// T,H fp16 (half2/lane); fp32 accumulate. 1 node per wave.
__global__ __launch_bounds__(256) void pull_agg1_kernel(const __half* __restrict__ T,
                                                        const int* __restrict__ col,
                                                        const unsigned int* __restrict__ cursor,
                                                        const unsigned int* __restrict__ deg,
                                                        const float* __restrict__ dinv,
                                                        const float* __restrict__ b1,
                                                        __half* __restrict__ H, int N) {
    int node = blockIdx.x * 4 + (threadIdx.x >> 6);
    if (node >= N) return;
    int lane = threadIdx.x & 63;
    unsigned int end = cursor[node];
    unsigned int e = end - deg[node];
    const __half2* Tv = (const __half2*)T;      // row stride 64 half2
    float2 acc = __half22float2(Tv[(size_t)node * 64 + lane]);   // self loop
    for (; e + 3 < end; e += 4) {               // 4 loads in flight
        int s0 = col[e], s1 = col[e + 1], s2 = col[e + 2], s3 = col[e + 3];
        float2 v0 = __half22float2(Tv[(size_t)s0 * 64 + lane]);
        float2 v1 = __half22float2(Tv[(size_t)s1 * 64 + lane]);
        float2 v2 = __half22float2(Tv[(size_t)s2 * 64 + lane]);
        float2 v3 = __half22float2(Tv[(size_t)s3 * 64 + lane]);
        acc.x += (v0.x + v1.x) + (v2.x + v3.x);
        acc.y += (v0.y + v1.y) + (v2.y + v3.y);
    }
    for (; e < end; ++e) {
        float2 v0 = __half22float2(Tv[(size_t)col[e] * 64 + lane]);
        acc.x += v0.x; acc.y += v0.y;
    }
    float w = dinv[node];
    float2 b = ((const float2*)b1)[lane];
    float hx = fmaxf(fmaf(w, acc.x, b.x), 0.f);
    float hy = fmaxf(fmaf(w, acc.y, b.y), 0.f);
    ((__half2*)H)[(size_t)node * 64 + lane] = __floats2half2_rn(hx, hy);
}

// --- pull layer 2 + logsoftmax: out[d] = lsm(dinv[d]*sum + b2), F=64 -------
// T fp16; 2 nodes per wave (32 lanes x half2 each); OUT fp32.
__global__ __launch_bounds__(256) void pull_agg2_kernel(const __half* __restrict__ T,
                                                        const int* __restrict__ col,
                                                        const unsigned int* __restrict__ cursor,
                                                        const unsigned int* __restrict__ deg,
                                                        const float* __restrict__ dinv,
                                                        const float* __restrict__ b2,
                                                        float* __restrict__ OUT, int N) {
    int node = blockIdx.x * 8 + (threadIdx.x >> 5);
    if (node >= N) return;
    int c2 = threadIdx.x & 31;                  // col pair
    unsigned int end = cursor[node];
    unsigned int e = end - deg[node];
    const __half2* Tv = (const __half2*)T;      // row stride 32 half2
    float2 acc = __half22float2(Tv[(size_t)node * 32 + c2]);     // self loop
    for (; e + 3 < end; e += 4) {
        float2 v0 = __half22float2(Tv[(size_t)col[e] * 32 + c2]);
        float2 v1 = __half22float2(Tv[(size_t)col[e + 1] * 32 + c2]);
        float2 v2 = __half22float2(Tv[(size_t)col[e + 2] * 32 + c2]);
        float2 v3 = __half22float2(Tv[(size_t)col[e + 3] * 32 + c2]);
        acc.x += (v0.x + v1.x) + (v2.x + v3.x);
        acc.y += (v0.y + v1.y) + (v2.y + v3.y);
    }
    for (; e < end; ++e) {
        float2 v0 = __half22float2(Tv[(size_t)col[e] * 32 + c2]);
        acc.x += v0.x; acc.y += v0.y;
    }
    float w = dinv[node];
    float2 b = ((const float2*)b2)[c2];
    float vx = fmaf(w, acc.x, b.x);
    float vy = fmaf(w, acc.y, b.y);
    // reduce across this node's 32 lanes (xor masks < 32 stay in-group)
    float m = fmaxf(vx, vy);
#pragma unroll
    for (int off = 16; off > 0; off >>= 1) m = fmaxf(m, __shfl_xor(m, off));
    float sum = __expf(vx - m) + __expf(vy - m);
#pragma unroll
    for (int off = 16; off > 0; off >>= 1) sum += __shfl_xor(sum, off);
    float ls = m + logf(sum);
    float2 o;
    o.x = vx - ls;
    o.y = vy - ls;
    ((float2*)OUT)[(size_t)node * 32 + c2] = o;
}

extern "C" void kernel_launch(void* const* d_in, const int* in_sizes, int n_in,
                              void* d_out, int out_size, void* d_ws, size_t ws_size,
                              hipStream_t stream) {
    const float* x   = (const float*)d_in[0];
    const int*   ei  = (const int*)d_in[1];   // int32 per harness contract
    const float* W1  = (const float*)d_in[2];
    const float* b1  = (const float*)d_in[3];
    const float* W2  = (const float*)d_in[4];
    const float* b2  = (const float*)d_in[5];
    float*       out = (float*)d_out;

    const int N = in_sizes[0] / 128;      // 100000
    const int E = in_sizes[1] / 2;        // 1600000
    const int* src = ei;
    const int* dst = ei + E;
    const int nb = (N + 255) / 256;       // scan blocks (<= 1024)
    const int NB = (N + BSIZE - 1) >> BSHIFT;   // dst buckets (196 <= 256)

    // workspace layout
    char* ws = (char*)d_ws;
    size_t off = 0;
    auto alloc = [&](size_t bytes) { void* p = ws + off; off = (off + bytes + 255) & ~(size_t)255; return p; };
    unsigned int* deg    = (unsigned int*)alloc((size_t)N * 4);
    float*        dinv   = (float*)alloc((size_t)N * 4);
    unsigned int* cursor = (unsigned int*)alloc((size_t)N * 4);
    unsigned int* bsum   = (unsigned int*)alloc(1024 * 4);
    unsigned int* bb     = (unsigned int*)alloc(257 * 4);      // bucket_base
    unsigned int* bf     = (unsigned int*)alloc(256 * 4);      // bucket_fill
    int*          col    = (int*)alloc((size_t)E * 4);
    __half*       A      = (__half*)alloc((size_t)N * 128 * 2); // T1'/T2' fp16
    __half*       B      = (__half*)alloc((size_t)N * 128 * 2); // h fp16
    unsigned int* ebuf   = (unsigned int*)alloc((size_t)E * 4); // separate (no aliasing this round)

    // 1. degree + dinv
    hipMemsetAsync(deg, 0, (size_t)N * 4, stream);
    deg_count_kernel<<<(E + 255) / 256, 256, 0, stream>>>(dst, E, deg);
    dinv_kernel<<<nb, 256, 0, stream>>>(deg, dinv, N);

    // 2. CSR build: scan -> rowstart; bucket partition; per-bucket scatter
    block_sum_kernel<<<nb, 256, 0, stream>>>(deg, N, bsum);
    scan_bsum_kernel<<<1, 1024, 0, stream>>>(bsum, nb);
    scan_final_kernel<<<nb, 256, 0, stream>>>(deg, bsum, N, cursor);
    bucket_init_kernel<<<2, 256, 0, stream>>>(cursor, bb, bf, N, NB, E);
    partition_kernel<<<(E + P2_T * P2_I - 1) / (P2_T * P2_I), P2_T, 0, stream>>>(src, dst, bf, ebuf, E, NB);
    bucket_scatter_kernel<<<NB, 256, 0, stream>>>(ebuf, bb, cursor, col, N);
    // now cursor[i] == rowend(i); rowstart(i) = cursor[i] - deg[i]

    // 3. T1' = dinv * (x @ W1) [fp16];  h = relu(dinv*(pull sum) + b1) [fp16]
    gemm1_kernel<<<(N + 63) / 64, 256, 0, stream>>>(x, W1, dinv, A, N);
    pull_agg1_kernel<<<(N + 3) / 4, 256, 0, stream>>>(A, col, cursor, deg, dinv, b1, B, N);

    // 4. T2' = dinv * (h @ W2) [fp16];  out = logsoftmax(dinv*(pull sum) + b2)
    gemm2_kernel<<<(N + 63) / 64, 256, 0, stream>>>(B, W2, dinv, A, N);
    pull_agg2_kernel<<<(N + 7) / 8, 256, 0, stream>>>(A, col, cursor, deg, dinv, b2, out, N);
}

// Round 8
// 344.133 us; speedup vs baseline: 12.7698x; 1.1647x over previous
//
#include <hip/hip_runtime.h>
#include <hip/hip_fp16.h>

// ---------------------------------------------------------------------------
// GCN 2-layer forward:  out = log_softmax( A_hat * relu(A_hat * (x W1) + b1) W2 + b2 )
// A_hat = D^-1/2 (A + I) D^-1/2, deg on dst. Edge index arrives as int32.
//
// R8: CSR build restructured. Old: global random-atomic deg_count + 3-kernel
// N-scan + bucket_init (14 dispatches total). New: 196-bin bucket histogram
// (LDS) -> 1-block scan -> partition -> bucket_scatter2 which derives per-node
// deg/dinv/rowptr in LDS from its own bucket's edges. 9 dispatches.
// fp16 intermediates (fp32 accumulate) from r7 kept.
// ---------------------------------------------------------------------------

#define BSHIFT 9
#define BSIZE  512            // nodes per bucket; NB = ceil(N/512) = 196 < 256
#define P2_T   1024
#define P2_I   16             // edges staged per thread in partition pass

static __device__ __forceinline__ void fma4(float4& a, float s, const float4& w) {
    a.x += s * w.x; a.y += s * w.y; a.z += s * w.z; a.w += s * w.w;
}

// --- pass 1: per-bucket edge counts (coalesced dst read, LDS histogram) ----
__global__ __launch_bounds__(256) void bucket_hist_kernel(const int* __restrict__ dst, int E,
                                                          unsigned int* __restrict__ bcount, int NB) {
    __shared__ unsigned int h[256];
    int t = threadIdx.x;
    h[t] = 0u;
    __syncthreads();
    for (int i = blockIdx.x * 256 + t; i < E; i += gridDim.x * 256)
        atomicAdd(&h[dst[i] >> BSHIFT], 1u);
    __syncthreads();
    if (t < NB && h[t]) atomicAdd(&bcount[t], h[t]);
}

// --- scan bucket counts -> bucket_base bb[0..NB], bucket_fill bf -----------
__global__ __launch_bounds__(256) void bucket_scan_kernel(const unsigned int* __restrict__ bcount,
                                                          unsigned int* __restrict__ bb,
                                                          unsigned int* __restrict__ bf,
                                                          int NB, int E) {
    __shared__ unsigned int s[256];
    int t = threadIdx.x;
    unsigned int v = (t < NB) ? bcount[t] : 0u;
    s[t] = v;
    __syncthreads();
    for (int off = 1; off < 256; off <<= 1) {
        unsigned int u = s[t];
        if (t >= off) u += s[t - off];
        __syncthreads();
        s[t] = u;
        __syncthreads();
    }
    if (t < NB) {
        unsigned int ex = s[t] - v;
        bb[t] = ex;
        bf[t] = ex;
    }
    if (t == 0) bb[NB] = (unsigned int)E;
}

// --- pass 2: partition edges into dst-buckets, packed src|dstLocal<<17 -----
__global__ __launch_bounds__(1024) void partition_kernel(const int* __restrict__ src,
                                                         const int* __restrict__ dst,
                                                         unsigned int* __restrict__ bucket_fill,
                                                         unsigned int* __restrict__ ebuf,
                                                         int E, int NB) {
    __shared__ unsigned int hist[256];
    __shared__ unsigned int cur[256];
    int t = threadIdx.x;
    if (t < 256) hist[t] = 0u;
    __syncthreads();
    size_t base = (size_t)blockIdx.x * (P2_T * P2_I);
    int sv[P2_I], dv[P2_I];
#pragma unroll
    for (int i = 0; i < P2_I; ++i) {
        size_t idx = base + (size_t)i * P2_T + t;
        if (idx < (size_t)E) {
            sv[i] = src[idx];
            dv[i] = dst[idx];
            atomicAdd(&hist[dv[i] >> BSHIFT], 1u);
        } else dv[i] = -1;
    }
    __syncthreads();
    if (t < NB && hist[t] > 0u) cur[t] = atomicAdd(&bucket_fill[t], hist[t]);
    __syncthreads();
#pragma unroll
    for (int i = 0; i < P2_I; ++i) {
        if (dv[i] >= 0) {
            int b = dv[i] >> BSHIFT;
            unsigned int pos = atomicAdd(&cur[b], 1u);
            ebuf[pos] = (unsigned int)sv[i] | ((unsigned int)(dv[i] & (BSIZE - 1)) << 17);
        }
    }
}

// --- pass 3: per-bucket deg/dinv/rowptr in LDS + scatter; cursor=rowend ----
__global__ __launch_bounds__(256) void bucket_scatter2_kernel(const unsigned int* __restrict__ ebuf,
                                                              const unsigned int* __restrict__ bb,
                                                              unsigned int* __restrict__ cursor,
                                                              unsigned int* __restrict__ deg,
                                                              float* __restrict__ dinv,
                                                              int* __restrict__ col, int N) {
    __shared__ unsigned int ldeg[BSIZE];
    __shared__ unsigned int lcur[BSIZE];
    __shared__ unsigned int part[256];
    int b = blockIdx.x, t = threadIdx.x;
    int node0 = b << BSHIFT;
    int nn = min(BSIZE, N - node0);
    ldeg[t] = 0u;
    ldeg[t + 256] = 0u;
    __syncthreads();
    unsigned int e0 = bb[b], e1 = bb[b + 1];
    // pass A: local degree histogram (LDS atomics)
    for (unsigned int e = e0 + t; e < e1; e += 256)
        atomicAdd(&ldeg[ebuf[e] >> 17], 1u);
    __syncthreads();
    // LDS exclusive scan of 512 degrees (pairs per thread)
    unsigned int a0 = ldeg[2 * t], a1 = ldeg[2 * t + 1];
    part[t] = a0 + a1;
    __syncthreads();
    for (int off = 1; off < 256; off <<= 1) {
        unsigned int u = part[t];
        if (t >= off) u += part[t - off];
        __syncthreads();
        part[t] = u;
        __syncthreads();
    }
    unsigned int ex = part[t] - (a0 + a1);
    lcur[2 * t]     = e0 + ex;
    lcur[2 * t + 1] = e0 + ex + a0;
    __syncthreads();
    // pass B: scatter into col via LDS cursors
    for (unsigned int e = e0 + t; e < e1; e += 256) {
        unsigned int p = ebuf[e];
        unsigned int pos = atomicAdd(&lcur[p >> 17], 1u);
        col[pos] = (int)(p & 0x1FFFFu);
    }
    __syncthreads();
    // emit per-node metadata: deg, dinv, cursor(=rowend)
    for (int i = t; i < nn; i += 256) {
        unsigned int d = ldeg[i];
        deg[node0 + i] = d;
        dinv[node0 + i] = rsqrtf((float)(d + 1u));
        cursor[node0 + i] = lcur[i];
    }
}

// --- GEMM1: Y[r,128] = f16( dinv[r] * (X[r,128] @ W[128,128]) ) ------------
__global__ __launch_bounds__(256, 4) void gemm1_kernel(const float* __restrict__ X,
                                                       const float* __restrict__ W,
                                                       const float* __restrict__ dinv,
                                                       __half* __restrict__ Y, int n) {
    constexpr int CG = 32, RS = 8, R = 8, KC = 32;
    __shared__ float4 Wl[KC * CG];   // 16 KB
    __shared__ float4 Xl[64 * 9];    // 9 KB, stride 9 -> banks 4r%32

    int t = threadIdx.x;
    int row0 = blockIdx.x * 64;
    int cg = t % CG, rs = t / CG;
    float4 acc[R];
#pragma unroll
    for (int r = 0; r < R; ++r) acc[r] = make_float4(0.f, 0.f, 0.f, 0.f);

    for (int kc = 0; kc < 4; ++kc) {
        for (int i = t; i < KC * CG; i += 256) {
            int k = i / CG, c = i % CG;
            Wl[i] = ((const float4*)W)[(size_t)(kc * KC + k) * CG + c];
        }
        for (int i = t; i < 64 * 8; i += 256) {
            int r = i >> 3, j = i & 7;
            int gr = row0 + r;
            float4 v = make_float4(0.f, 0.f, 0.f, 0.f);
            if (gr < n) v = ((const float4*)X)[(size_t)gr * 32 + kc * 8 + j];
            Xl[r * 9 + j] = v;
        }
        __syncthreads();
#pragma unroll
        for (int k4 = 0; k4 < 8; ++k4) {
            float4 wv[4];
#pragma unroll
            for (int kk = 0; kk < 4; ++kk) wv[kk] = Wl[(k4 * 4 + kk) * CG + cg];
#pragma unroll
            for (int r = 0; r < R; ++r) {
                float4 xv = Xl[(rs + RS * r) * 9 + k4];
                fma4(acc[r], xv.x, wv[0]);
                fma4(acc[r], xv.y, wv[1]);
                fma4(acc[r], xv.z, wv[2]);
                fma4(acc[r], xv.w, wv[3]);
            }
        }
        __syncthreads();
    }
#pragma unroll
    for (int r = 0; r < R; ++r) {
        int gr = row0 + rs + RS * r;
        if (gr < n) {
            float w = dinv[gr];
            float4 a = acc[r];
            __half2* Yv = (__half2*)(Y + (size_t)gr * 128 + cg * 4);
            Yv[0] = __floats2half2_rn(a.x * w, a.y * w);
            Yv[1] = __floats2half2_rn(a.z * w, a.w * w);
        }
    }
}

// --- GEMM2: Y[r,64] = f16( dinv[r] * (Xh[r,128] @ W[128,64]) ) -------------
__global__ __launch_bounds__(256, 4) void gemm2_kernel(const __half* __restrict__ X,
                                                       const float* __restrict__ W,
                                                       const float* __restrict__ dinv,
                                                       __half* __restrict__ Y, int n) {
    constexpr int CG = 16, RS = 16, R = 4, KC = 32;
    __shared__ float4 Wl[KC * CG];   // 8 KB
    __shared__ float4 Xl[64 * 9];    // 9 KB

    int t = threadIdx.x;
    int row0 = blockIdx.x * 64;
    int cg = t % CG, rs = t / CG;
    float4 acc[R];
#pragma unroll
    for (int r = 0; r < R; ++r) acc[r] = make_float4(0.f, 0.f, 0.f, 0.f);

    for (int kc = 0; kc < 4; ++kc) {
        for (int i = t; i < KC * CG; i += 256) {
            int k = i / CG, c = i % CG;
            Wl[i] = ((const float4*)W)[(size_t)(kc * KC + k) * CG + c];
        }
        for (int i = t; i < 64 * 8; i += 256) {
            int r = i >> 3, j = i & 7;
            int gr = row0 + r;
            float4 v = make_float4(0.f, 0.f, 0.f, 0.f);
            if (gr < n) {
                const __half2* xp = (const __half2*)(X + (size_t)gr * 128 + (kc * 8 + j) * 4);
                float2 lo = __half22float2(xp[0]);
                float2 hi = __half22float2(xp[1]);
                v = make_float4(lo.x, lo.y, hi.x, hi.y);
            }
            Xl[r * 9 + j] = v;
        }
        __syncthreads();
#pragma unroll
        for (int k4 = 0; k4 < 8; ++k4) {
            float4 wv[4];
#pragma unroll
            for (int kk = 0; kk < 4; ++kk) wv[kk] = Wl[(k4 * 4 + kk) * CG + cg];
#pragma unroll
            for (int r = 0; r < R; ++r) {
                float4 xv = Xl[(rs + RS * r) * 9 + k4];
                fma4(acc[r], xv.x, wv[0]);
                fma4(acc[r], xv.y, wv[1]);
                fma4(acc[r], xv.z, wv[2]);
                fma4(acc[r], xv.w, wv[3]);
            }
        }
        __syncthreads();
    }
#pragma unroll
    for (int r = 0; r < R; ++r) {
        int gr = row0 + rs + RS * r;
        if (gr < n) {
            float w = dinv[gr];
            float4 a = acc[r];
            __half2* Yv = (__half2*)(Y + (size_t)gr * 64 + cg * 4);
            Yv[0] = __floats2half2_rn(a.x * w, a.y * w);
            Yv[1] = __floats2half2_rn(a.z * w, a.w * w);
        }
    }
}

// --- pull layer 1: H[d] = relu(dinv[d]*(T'[d] + sum T'[col]) + b1), F=128 --
__global__ __launch_bounds__(256) void pull_agg1_kernel(const __half* __restrict__ T,
                                                        const int* __restrict__ col,
                                                        const unsigned int* __restrict__ cursor,
                                                        const unsigned int* __restrict__ deg,
                                                        const float* __restrict__ dinv,
                                                        const float* __restrict__ b1,
                                                        __half* __restrict__ H, int N) {
    int node = blockIdx.x * 4 + (threadIdx.x >> 6);
    if (node >= N) return;
    int lane = threadIdx.x & 63;
    unsigned int end = cursor[node];
    unsigned int e = end - deg[node];
    const __half2* Tv = (const __half2*)T;      // row stride 64 half2
    float2 acc = __half22float2(Tv[(size_t)node * 64 + lane]);   // self loop
    for (; e + 3 < end; e += 4) {               // 4 loads in flight
        int s0 = col[e], s1 = col[e + 1], s2 = col[e + 2], s3 = col[e + 3];
        float2 v0 = __half22float2(Tv[(size_t)s0 * 64 + lane]);
        float2 v1 = __half22float2(Tv[(size_t)s1 * 64 + lane]);
        float2 v2 = __half22float2(Tv[(size_t)s2 * 64 + lane]);
        float2 v3 = __half22float2(Tv[(size_t)s3 * 64 + lane]);
        acc.x += (v0.x + v1.x) + (v2.x + v3.x);
        acc.y += (v0.y + v1.y) + (v2.y + v3.y);
    }
    for (; e < end; ++e) {
        float2 v0 = __half22float2(Tv[(size_t)col[e] * 64 + lane]);
        acc.x += v0.x; acc.y += v0.y;
    }
    float w = dinv[node];
    float2 b = ((const float2*)b1)[lane];
    float hx = fmaxf(fmaf(w, acc.x, b.x), 0.f);
    float hy = fmaxf(fmaf(w, acc.y, b.y), 0.f);
    ((__half2*)H)[(size_t)node * 64 + lane] = __floats2half2_rn(hx, hy);
}

// --- pull layer 2 + logsoftmax: out[d] = lsm(dinv[d]*sum + b2), F=64 -------
__global__ __launch_bounds__(256) void pull_agg2_kernel(const __half* __restrict__ T,
                                                        const int* __restrict__ col,
                                                        const unsigned int* __restrict__ cursor,
                                                        const unsigned int* __restrict__ deg,
                                                        const float* __restrict__ dinv,
                                                        const float* __restrict__ b2,
                                                        float* __restrict__ OUT, int N) {
    int node = blockIdx.x * 8 + (threadIdx.x >> 5);
    if (node >= N) return;
    int c2 = threadIdx.x & 31;                  // col pair
    unsigned int end = cursor[node];
    unsigned int e = end - deg[node];
    const __half2* Tv = (const __half2*)T;      // row stride 32 half2
    float2 acc = __half22float2(Tv[(size_t)node * 32 + c2]);     // self loop
    for (; e + 3 < end; e += 4) {
        float2 v0 = __half22float2(Tv[(size_t)col[e] * 32 + c2]);
        float2 v1 = __half22float2(Tv[(size_t)col[e + 1] * 32 + c2]);
        float2 v2 = __half22float2(Tv[(size_t)col[e + 2] * 32 + c2]);
        float2 v3 = __half22float2(Tv[(size_t)col[e + 3] * 32 + c2]);
        acc.x += (v0.x + v1.x) + (v2.x + v3.x);
        acc.y += (v0.y + v1.y) + (v2.y + v3.y);
    }
    for (; e < end; ++e) {
        float2 v0 = __half22float2(Tv[(size_t)col[e] * 32 + c2]);
        acc.x += v0.x; acc.y += v0.y;
    }
    float w = dinv[node];
    float2 b = ((const float2*)b2)[c2];
    float vx = fmaf(w, acc.x, b.x);
    float vy = fmaf(w, acc.y, b.y);
    // reduce across this node's 32 lanes (xor masks < 32 stay in-group)
    float m = fmaxf(vx, vy);
#pragma unroll
    for (int off = 16; off > 0; off >>= 1) m = fmaxf(m, __shfl_xor(m, off));
    float sum = __expf(vx - m) + __expf(vy - m);
#pragma unroll
    for (int off = 16; off > 0; off >>= 1) sum += __shfl_xor(sum, off);
    float ls = m + logf(sum);
    float2 o;
    o.x = vx - ls;
    o.y = vy - ls;
    ((float2*)OUT)[(size_t)node * 32 + c2] = o;
}

extern "C" void kernel_launch(void* const* d_in, const int* in_sizes, int n_in,
                              void* d_out, int out_size, void* d_ws, size_t ws_size,
                              hipStream_t stream) {
    const float* x   = (const float*)d_in[0];
    const int*   ei  = (const int*)d_in[1];   // int32 per harness contract
    const float* W1  = (const float*)d_in[2];
    const float* b1  = (const float*)d_in[3];
    const float* W2  = (const float*)d_in[4];
    const float* b2  = (const float*)d_in[5];
    float*       out = (float*)d_out;

    const int N = in_sizes[0] / 128;      // 100000
    const int E = in_sizes[1] / 2;        // 1600000
    const int* src = ei;
    const int* dst = ei + E;
    const int NB = (N + BSIZE - 1) >> BSHIFT;   // dst buckets (196 <= 256)

    // workspace layout
    char* ws = (char*)d_ws;
    size_t off = 0;
    auto alloc = [&](size_t bytes) { void* p = ws + off; off = (off + bytes + 255) & ~(size_t)255; return p; };
    unsigned int* deg    = (unsigned int*)alloc((size_t)N * 4);
    float*        dinv   = (float*)alloc((size_t)N * 4);
    unsigned int* cursor = (unsigned int*)alloc((size_t)N * 4);
    unsigned int* bcount = (unsigned int*)alloc(256 * 4);
    unsigned int* bb     = (unsigned int*)alloc(257 * 4);       // bucket_base
    unsigned int* bf     = (unsigned int*)alloc(256 * 4);       // bucket_fill
    int*          col    = (int*)alloc((size_t)E * 4);
    __half*       A      = (__half*)alloc((size_t)N * 128 * 2); // T1'/T2' fp16
    __half*       B      = (__half*)alloc((size_t)N * 128 * 2); // h fp16
    unsigned int* ebuf   = (unsigned int*)alloc((size_t)E * 4);

    // 1. CSR build: bucket hist -> scan -> partition -> per-bucket scatter
    hipMemsetAsync(bcount, 0, 256 * 4, stream);
    bucket_hist_kernel<<<(E + 4095) / 4096, 256, 0, stream>>>(dst, E, bcount, NB);
    bucket_scan_kernel<<<1, 256, 0, stream>>>(bcount, bb, bf, NB, E);
    partition_kernel<<<(E + P2_T * P2_I - 1) / (P2_T * P2_I), P2_T, 0, stream>>>(src, dst, bf, ebuf, E, NB);
    bucket_scatter2_kernel<<<NB, 256, 0, stream>>>(ebuf, bb, cursor, deg, dinv, col, N);
    // now cursor[i] == rowend(i); rowstart(i) = cursor[i] - deg[i]; dinv ready

    // 2. T1' = dinv * (x @ W1) [fp16];  h = relu(dinv*(pull sum) + b1) [fp16]
    gemm1_kernel<<<(N + 63) / 64, 256, 0, stream>>>(x, W1, dinv, A, N);
    pull_agg1_kernel<<<(N + 3) / 4, 256, 0, stream>>>(A, col, cursor, deg, dinv, b1, B, N);

    // 3. T2' = dinv * (h @ W2) [fp16];  out = logsoftmax(dinv*(pull sum) + b2)
    gemm2_kernel<<<(N + 63) / 64, 256, 0, stream>>>(B, W2, dinv, A, N);
    pull_agg2_kernel<<<(N + 7) / 8, 256, 0, stream>>>(A, col, cursor, deg, dinv, b2, out, N);
}

// Round 9
// 318.964 us; speedup vs baseline: 13.7774x; 1.0789x over previous
//
#include <hip/hip_runtime.h>
#include <hip/hip_fp16.h>

// ---------------------------------------------------------------------------
// GCN 2-layer forward:  out = log_softmax( A_hat * relu(A_hat * (x W1) + b1) W2 + b2 )
// A_hat = D^-1/2 (A + I) D^-1/2, deg on dst. Edge index arrives as int32.
//
// R9: GEMMs moved from fp32 VALU (157 TF) to MFMA f32_16x16x32_f16.
// W1/W2 pre-swizzled into fragment order (B-frag = one contiguous half8,
// L2-resident); A-frags loaded directly from global (lane pattern covers
// full lines). Verified layouts (learn_hip m89/m91/m120):
//   A[m=lane&15][k=(lane>>4)*8+j],  B[k=(lane>>4)*8+j][n=lane&15],
//   D: col=lane&15, row=(lane>>4)*4+reg.
// CSR build + fp16 pull kernels unchanged from r8.
// ---------------------------------------------------------------------------

#define BSHIFT 9
#define BSIZE  512            // nodes per bucket; NB = ceil(N/512) = 196 < 256
#define P2_T   1024
#define P2_I   16             // edges staged per thread in partition pass

using half8 = __attribute__((ext_vector_type(8))) _Float16;
using f32x4 = __attribute__((ext_vector_type(4))) float;

// --- pass 1: per-bucket edge counts (coalesced dst read, LDS histogram) ----
__global__ __launch_bounds__(256) void bucket_hist_kernel(const int* __restrict__ dst, int E,
                                                          unsigned int* __restrict__ bcount, int NB) {
    __shared__ unsigned int h[256];
    int t = threadIdx.x;
    h[t] = 0u;
    __syncthreads();
    for (int i = blockIdx.x * 256 + t; i < E; i += gridDim.x * 256)
        atomicAdd(&h[dst[i] >> BSHIFT], 1u);
    __syncthreads();
    if (t < NB && h[t]) atomicAdd(&bcount[t], h[t]);
}

// --- scan bucket counts -> bucket_base bb[0..NB], bucket_fill bf -----------
__global__ __launch_bounds__(256) void bucket_scan_kernel(const unsigned int* __restrict__ bcount,
                                                          unsigned int* __restrict__ bb,
                                                          unsigned int* __restrict__ bf,
                                                          int NB, int E) {
    __shared__ unsigned int s[256];
    int t = threadIdx.x;
    unsigned int v = (t < NB) ? bcount[t] : 0u;
    s[t] = v;
    __syncthreads();
    for (int off = 1; off < 256; off <<= 1) {
        unsigned int u = s[t];
        if (t >= off) u += s[t - off];
        __syncthreads();
        s[t] = u;
        __syncthreads();
    }
    if (t < NB) {
        unsigned int ex = s[t] - v;
        bb[t] = ex;
        bf[t] = ex;
    }
    if (t == 0) bb[NB] = (unsigned int)E;
}

// --- pass 2: partition edges into dst-buckets, packed src|dstLocal<<17 -----
__global__ __launch_bounds__(1024) void partition_kernel(const int* __restrict__ src,
                                                         const int* __restrict__ dst,
                                                         unsigned int* __restrict__ bucket_fill,
                                                         unsigned int* __restrict__ ebuf,
                                                         int E, int NB) {
    __shared__ unsigned int hist[256];
    __shared__ unsigned int cur[256];
    int t = threadIdx.x;
    if (t < 256) hist[t] = 0u;
    __syncthreads();
    size_t base = (size_t)blockIdx.x * (P2_T * P2_I);
    int sv[P2_I], dv[P2_I];
#pragma unroll
    for (int i = 0; i < P2_I; ++i) {
        size_t idx = base + (size_t)i * P2_T + t;
        if (idx < (size_t)E) {
            sv[i] = src[idx];
            dv[i] = dst[idx];
            atomicAdd(&hist[dv[i] >> BSHIFT], 1u);
        } else dv[i] = -1;
    }
    __syncthreads();
    if (t < NB && hist[t] > 0u) cur[t] = atomicAdd(&bucket_fill[t], hist[t]);
    __syncthreads();
#pragma unroll
    for (int i = 0; i < P2_I; ++i) {
        if (dv[i] >= 0) {
            int b = dv[i] >> BSHIFT;
            unsigned int pos = atomicAdd(&cur[b], 1u);
            ebuf[pos] = (unsigned int)sv[i] | ((unsigned int)(dv[i] & (BSIZE - 1)) << 17);
        }
    }
}

// --- pass 3: per-bucket deg/dinv/rowptr in LDS + scatter; cursor=rowend ----
__global__ __launch_bounds__(256) void bucket_scatter2_kernel(const unsigned int* __restrict__ ebuf,
                                                              const unsigned int* __restrict__ bb,
                                                              unsigned int* __restrict__ cursor,
                                                              unsigned int* __restrict__ deg,
                                                              float* __restrict__ dinv,
                                                              int* __restrict__ col, int N) {
    __shared__ unsigned int ldeg[BSIZE];
    __shared__ unsigned int lcur[BSIZE];
    __shared__ unsigned int part[256];
    int b = blockIdx.x, t = threadIdx.x;
    int node0 = b << BSHIFT;
    int nn = min(BSIZE, N - node0);
    ldeg[t] = 0u;
    ldeg[t + 256] = 0u;
    __syncthreads();
    unsigned int e0 = bb[b], e1 = bb[b + 1];
    for (unsigned int e = e0 + t; e < e1; e += 256)
        atomicAdd(&ldeg[ebuf[e] >> 17], 1u);
    __syncthreads();
    unsigned int a0 = ldeg[2 * t], a1 = ldeg[2 * t + 1];
    part[t] = a0 + a1;
    __syncthreads();
    for (int off = 1; off < 256; off <<= 1) {
        unsigned int u = part[t];
        if (t >= off) u += part[t - off];
        __syncthreads();
        part[t] = u;
        __syncthreads();
    }
    unsigned int ex = part[t] - (a0 + a1);
    lcur[2 * t]     = e0 + ex;
    lcur[2 * t + 1] = e0 + ex + a0;
    __syncthreads();
    for (unsigned int e = e0 + t; e < e1; e += 256) {
        unsigned int p = ebuf[e];
        unsigned int pos = atomicAdd(&lcur[p >> 17], 1u);
        col[pos] = (int)(p & 0x1FFFFu);
    }
    __syncthreads();
    for (int i = t; i < nn; i += 256) {
        unsigned int d = ldeg[i];
        deg[node0 + i] = d;
        dinv[node0 + i] = rsqrtf((float)(d + 1u));
        cursor[node0 + i] = lcur[i];
    }
}

// --- swizzle W1 (128x128) and W2 (128x64) into MFMA B-fragment order -------
// w1s[((c*4+s)*64+l)*8+j] = W[k][n], k=(l>>4)*8+j+32s, n=16c+(l&15)
__global__ __launch_bounds__(256) void swizzle_w_kernel(const float* __restrict__ W1,
                                                        const float* __restrict__ W2,
                                                        __half* __restrict__ w1s,
                                                        __half* __restrict__ w2s) {
    int t = threadIdx.x;
    for (int i = t; i < 8 * 4 * 64 * 8; i += 256) {   // W1: 8 col-tiles
        int j = i & 7, l = (i >> 3) & 63, s = (i >> 9) & 3, c = i >> 11;
        int k = ((l >> 4) * 8) + j + 32 * s;
        int nn = 16 * c + (l & 15);
        w1s[i] = __float2half(W1[k * 128 + nn]);
    }
    for (int i = t; i < 4 * 4 * 64 * 8; i += 256) {   // W2: 4 col-tiles
        int j = i & 7, l = (i >> 3) & 63, s = (i >> 9) & 3, c = i >> 11;
        int k = ((l >> 4) * 8) + j + 32 * s;
        int nn = 16 * c + (l & 15);
        w2s[i] = __float2half(W2[k * 64 + nn]);
    }
}

// --- GEMM1 (MFMA): Y[r,128] = f16( dinv[r] * (X[r,128] @ W1) ), X fp32 -----
__global__ __launch_bounds__(256) void gemm1_mfma_kernel(const float* __restrict__ X,
                                                         const __half* __restrict__ w1s,
                                                         const float* __restrict__ dinv,
                                                         __half* __restrict__ Y, int n) {
    int t = threadIdx.x;
    int wave = t >> 6, lane = t & 63;
    int quad = lane >> 4, m = lane & 15;
    int rowbase = blockIdx.x * 64 + wave * 16;
    int arow = rowbase + m;
    bool aok = arow < n;
    const float* xr = X + (size_t)arow * 128 + quad * 8;

    half8 afrag[4];
#pragma unroll
    for (int s = 0; s < 4; ++s) {
        float4 p0 = make_float4(0.f, 0.f, 0.f, 0.f), p1 = p0;
        if (aok) {
            p0 = *(const float4*)(xr + s * 32);
            p1 = *(const float4*)(xr + s * 32 + 4);
        }
        afrag[s][0] = (_Float16)p0.x; afrag[s][1] = (_Float16)p0.y;
        afrag[s][2] = (_Float16)p0.z; afrag[s][3] = (_Float16)p0.w;
        afrag[s][4] = (_Float16)p1.x; afrag[s][5] = (_Float16)p1.y;
        afrag[s][6] = (_Float16)p1.z; afrag[s][7] = (_Float16)p1.w;
    }

    const half8* bp = (const half8*)w1s;
    f32x4 acc[8];
#pragma unroll
    for (int c = 0; c < 8; ++c) acc[c] = (f32x4){0.f, 0.f, 0.f, 0.f};
#pragma unroll
    for (int c = 0; c < 8; ++c)
#pragma unroll
        for (int s = 0; s < 4; ++s)
            acc[c] = __builtin_amdgcn_mfma_f32_16x16x32_f16(afrag[s], bp[(c * 4 + s) * 64 + lane], acc[c], 0, 0, 0);

#pragma unroll
    for (int i = 0; i < 4; ++i) {
        int row = rowbase + quad * 4 + i;
        if (row < n) {
            float w = dinv[row];
            __half* yr = Y + (size_t)row * 128 + m;
#pragma unroll
            for (int c = 0; c < 8; ++c) yr[c * 16] = __float2half(acc[c][i] * w);
        }
    }
}

// --- GEMM2 (MFMA): Y[r,64] = f16( dinv[r] * (Xh[r,128] @ W2) ), X fp16 -----
__global__ __launch_bounds__(256) void gemm2_mfma_kernel(const __half* __restrict__ X,
                                                         const __half* __restrict__ w2s,
                                                         const float* __restrict__ dinv,
                                                         __half* __restrict__ Y, int n) {
    int t = threadIdx.x;
    int wave = t >> 6, lane = t & 63;
    int quad = lane >> 4, m = lane & 15;
    int rowbase = blockIdx.x * 64 + wave * 16;
    int arow = rowbase + m;
    bool aok = arow < n;
    const __half* xr = X + (size_t)arow * 128 + quad * 8;

    half8 afrag[4];
#pragma unroll
    for (int s = 0; s < 4; ++s) {
        if (aok) afrag[s] = *(const half8*)(xr + s * 32);
        else     afrag[s] = (half8){0, 0, 0, 0, 0, 0, 0, 0};
    }

    const half8* bp = (const half8*)w2s;
    f32x4 acc[4];
#pragma unroll
    for (int c = 0; c < 4; ++c) acc[c] = (f32x4){0.f, 0.f, 0.f, 0.f};
#pragma unroll
    for (int c = 0; c < 4; ++c)
#pragma unroll
        for (int s = 0; s < 4; ++s)
            acc[c] = __builtin_amdgcn_mfma_f32_16x16x32_f16(afrag[s], bp[(c * 4 + s) * 64 + lane], acc[c], 0, 0, 0);

#pragma unroll
    for (int i = 0; i < 4; ++i) {
        int row = rowbase + quad * 4 + i;
        if (row < n) {
            float w = dinv[row];
            __half* yr = Y + (size_t)row * 64 + m;
#pragma unroll
            for (int c = 0; c < 4; ++c) yr[c * 16] = __float2half(acc[c][i] * w);
        }
    }
}

// --- pull layer 1: H[d] = relu(dinv[d]*(T'[d] + sum T'[col]) + b1), F=128 --
__global__ __launch_bounds__(256) void pull_agg1_kernel(const __half* __restrict__ T,
                                                        const int* __restrict__ col,
                                                        const unsigned int* __restrict__ cursor,
                                                        const unsigned int* __restrict__ deg,
                                                        const float* __restrict__ dinv,
                                                        const float* __restrict__ b1,
                                                        __half* __restrict__ H, int N) {
    int node = blockIdx.x * 4 + (threadIdx.x >> 6);
    if (node >= N) return;
    int lane = threadIdx.x & 63;
    unsigned int end = cursor[node];
    unsigned int e = end - deg[node];
    const __half2* Tv = (const __half2*)T;      // row stride 64 half2
    float2 acc = __half22float2(Tv[(size_t)node * 64 + lane]);   // self loop
    for (; e + 3 < end; e += 4) {               // 4 loads in flight
        int s0 = col[e], s1 = col[e + 1], s2 = col[e + 2], s3 = col[e + 3];
        float2 v0 = __half22float2(Tv[(size_t)s0 * 64 + lane]);
        float2 v1 = __half22float2(Tv[(size_t)s1 * 64 + lane]);
        float2 v2 = __half22float2(Tv[(size_t)s2 * 64 + lane]);
        float2 v3 = __half22float2(Tv[(size_t)s3 * 64 + lane]);
        acc.x += (v0.x + v1.x) + (v2.x + v3.x);
        acc.y += (v0.y + v1.y) + (v2.y + v3.y);
    }
    for (; e < end; ++e) {
        float2 v0 = __half22float2(Tv[(size_t)col[e] * 64 + lane]);
        acc.x += v0.x; acc.y += v0.y;
    }
    float w = dinv[node];
    float2 b = ((const float2*)b1)[lane];
    float hx = fmaxf(fmaf(w, acc.x, b.x), 0.f);
    float hy = fmaxf(fmaf(w, acc.y, b.y), 0.f);
    ((__half2*)H)[(size_t)node * 64 + lane] = __floats2half2_rn(hx, hy);
}

// --- pull layer 2 + logsoftmax: out[d] = lsm(dinv[d]*sum + b2), F=64 -------
__global__ __launch_bounds__(256) void pull_agg2_kernel(const __half* __restrict__ T,
                                                        const int* __restrict__ col,
                                                        const unsigned int* __restrict__ cursor,
                                                        const unsigned int* __restrict__ deg,
                                                        const float* __restrict__ dinv,
                                                        const float* __restrict__ b2,
                                                        float* __restrict__ OUT, int N) {
    int node = blockIdx.x * 8 + (threadIdx.x >> 5);
    if (node >= N) return;
    int c2 = threadIdx.x & 31;                  // col pair
    unsigned int end = cursor[node];
    unsigned int e = end - deg[node];
    const __half2* Tv = (const __half2*)T;      // row stride 32 half2
    float2 acc = __half22float2(Tv[(size_t)node * 32 + c2]);     // self loop
    for (; e + 3 < end; e += 4) {
        float2 v0 = __half22float2(Tv[(size_t)col[e] * 32 + c2]);
        float2 v1 = __half22float2(Tv[(size_t)col[e + 1] * 32 + c2]);
        float2 v2 = __half22float2(Tv[(size_t)col[e + 2] * 32 + c2]);
        float2 v3 = __half22float2(Tv[(size_t)col[e + 3] * 32 + c2]);
        acc.x += (v0.x + v1.x) + (v2.x + v3.x);
        acc.y += (v0.y + v1.y) + (v2.y + v3.y);
    }
    for (; e < end; ++e) {
        float2 v0 = __half22float2(Tv[(size_t)col[e] * 32 + c2]);
        acc.x += v0.x; acc.y += v0.y;
    }
    float w = dinv[node];
    float2 b = ((const float2*)b2)[c2];
    float vx = fmaf(w, acc.x, b.x);
    float vy = fmaf(w, acc.y, b.y);
    float m = fmaxf(vx, vy);
#pragma unroll
    for (int off = 16; off > 0; off >>= 1) m = fmaxf(m, __shfl_xor(m, off));
    float sum = __expf(vx - m) + __expf(vy - m);
#pragma unroll
    for (int off = 16; off > 0; off >>= 1) sum += __shfl_xor(sum, off);
    float ls = m + logf(sum);
    float2 o;
    o.x = vx - ls;
    o.y = vy - ls;
    ((float2*)OUT)[(size_t)node * 32 + c2] = o;
}

extern "C" void kernel_launch(void* const* d_in, const int* in_sizes, int n_in,
                              void* d_out, int out_size, void* d_ws, size_t ws_size,
                              hipStream_t stream) {
    const float* x   = (const float*)d_in[0];
    const int*   ei  = (const int*)d_in[1];   // int32 per harness contract
    const float* W1  = (const float*)d_in[2];
    const float* b1  = (const float*)d_in[3];
    const float* W2  = (const float*)d_in[4];
    const float* b2  = (const float*)d_in[5];
    float*       out = (float*)d_out;

    const int N = in_sizes[0] / 128;      // 100000
    const int E = in_sizes[1] / 2;        // 1600000
    const int* src = ei;
    const int* dst = ei + E;
    const int NB = (N + BSIZE - 1) >> BSHIFT;   // dst buckets (196 <= 256)

    // workspace layout
    char* ws = (char*)d_ws;
    size_t off = 0;
    auto alloc = [&](size_t bytes) { void* p = ws + off; off = (off + bytes + 255) & ~(size_t)255; return p; };
    unsigned int* deg    = (unsigned int*)alloc((size_t)N * 4);
    float*        dinv   = (float*)alloc((size_t)N * 4);
    unsigned int* cursor = (unsigned int*)alloc((size_t)N * 4);
    unsigned int* bcount = (unsigned int*)alloc(256 * 4);
    unsigned int* bb     = (unsigned int*)alloc(257 * 4);       // bucket_base
    unsigned int* bf     = (unsigned int*)alloc(256 * 4);       // bucket_fill
    __half*       w1s    = (__half*)alloc(128 * 128 * 2);       // swizzled W1
    __half*       w2s    = (__half*)alloc(128 * 64 * 2);        // swizzled W2
    int*          col    = (int*)alloc((size_t)E * 4);
    __half*       A      = (__half*)alloc((size_t)N * 128 * 2); // T1'/T2' fp16
    __half*       B      = (__half*)alloc((size_t)N * 128 * 2); // h fp16
    unsigned int* ebuf   = (unsigned int*)alloc((size_t)E * 4);

    // 1. CSR build: bucket hist -> scan -> partition -> per-bucket scatter
    hipMemsetAsync(bcount, 0, 256 * 4, stream);
    bucket_hist_kernel<<<(E + 4095) / 4096, 256, 0, stream>>>(dst, E, bcount, NB);
    bucket_scan_kernel<<<1, 256, 0, stream>>>(bcount, bb, bf, NB, E);
    partition_kernel<<<(E + P2_T * P2_I - 1) / (P2_T * P2_I), P2_T, 0, stream>>>(src, dst, bf, ebuf, E, NB);
    bucket_scatter2_kernel<<<NB, 256, 0, stream>>>(ebuf, bb, cursor, deg, dinv, col, N);
    // now cursor[i] == rowend(i); rowstart(i) = cursor[i] - deg[i]; dinv ready

    // 1b. swizzle weights into MFMA fragment order (runs alongside CSR chain)
    swizzle_w_kernel<<<1, 256, 0, stream>>>(W1, W2, w1s, w2s);

    // 2. T1' = dinv * (x @ W1) [MFMA, fp16 out];  h = relu(dinv*(pull) + b1)
    gemm1_mfma_kernel<<<(N + 63) / 64, 256, 0, stream>>>(x, w1s, dinv, A, N);
    pull_agg1_kernel<<<(N + 3) / 4, 256, 0, stream>>>(A, col, cursor, deg, dinv, b1, B, N);

    // 3. T2' = dinv * (h @ W2) [MFMA];  out = logsoftmax(dinv*(pull) + b2)
    gemm2_mfma_kernel<<<(N + 63) / 64, 256, 0, stream>>>(B, w2s, dinv, A, N);
    pull_agg2_kernel<<<(N + 7) / 8, 256, 0, stream>>>(A, col, cursor, deg, dinv, b2, out, N);
}